// Round 14
// baseline (909.252 us; speedup 1.0000x reference)
//
#include <hip/hip_runtime.h>
#include <hip/hip_bf16.h>
#include <math.h>

#define BATCH 256
#define CCH 768
#define LCH 64
#define PP 81
#define CHW 3072   // elems per chunk image: 96 rows x 32 ch

typedef __attribute__((ext_vector_type(8))) short short8v;
typedef __attribute__((ext_vector_type(4))) float f32x4;

// ---------------- P: merged weight prep (compose + wprep + fcprep) ----------
__global__ __launch_bounds__(256) void k_prep(
    const float* __restrict__ W11, const float* __restrict__ Wh2,
    const float* __restrict__ Wl1, const float* __restrict__ bh2,
    const float* __restrict__ bl1, const float* __restrict__ b11,
    const float* __restrict__ Wh1, const float* __restrict__ Wb,
    const float* __restrict__ Wfc1, const float* __restrict__ Wfc2,
    __hip_bfloat16* __restrict__ WAp, __hip_bfloat16* __restrict__ WBp,
    __hip_bfloat16* __restrict__ Wh1p, float* __restrict__ beff,
    __hip_bfloat16* __restrict__ Wp,
    float* __restrict__ T1, float* __restrict__ T2)
{
    int blk = blockIdx.x;
    int t = threadIdx.x;
    if (blk < CCH) {
        int o = blk;
        int ot = o >> 4, l15o = o & 15;
        const float* w11row = W11 + (size_t)o * CCH;
        for (int c = t; c < CCH; c += 256) {
            float s = 0.f;
            for (int k = 0; k < 512; ++k) s = fmaf(w11row[k], Wh2[(size_t)k*CCH + c], s);
            int ch = c >> 5, kg = (c >> 3) & 3, j = c & 7;
            size_t idx = (((size_t)ot*24 + ch) << 9) + (size_t)(kg*16 + l15o)*8 + j;
            WAp[idx]  = __float2bfloat16(s);
            Wh1p[idx] = __float2bfloat16(Wh1[(size_t)o*CCH + c]);
        }
        if (t < LCH) {
            float s = 0.f;
            for (int k = 0; k < 256; ++k) s = fmaf(w11row[512+k], Wl1[k*LCH + t], s);
            int ch = t >> 5, kg = (t >> 3) & 3, j = t & 7;
            size_t idx = (((size_t)ot*2 + ch) << 9) + (size_t)(kg*16 + l15o)*8 + j;
            WBp[idx] = __float2bfloat16(s);
        }
        if (t == 0) {
            float s = b11[o];
            for (int k = 0; k < 512; ++k) s = fmaf(w11row[k], bh2[k], s);
            for (int k = 0; k < 256; ++k) s = fmaf(w11row[512+k], bl1[k], s);
            beff[o] = s;
        }
    } else if (blk < CCH + 288) {
        int id = blk - CCH;
        int ot = id / 6;
        int i  = (id - ot*6)*256 + t;
        int oi = i / 96, c8 = i - oi*96;
        const float* src = Wb + ((size_t)(ot*16 + oi)*CCH + c8*8)*9;
        int ch = c8 >> 2;
        int lane8 = (((c8 & 3)*16) + oi)*8;
        #pragma unroll
        for (int tt = 0; tt < 9; ++tt) {
            short8v v;
            #pragma unroll
            for (int j = 0; j < 8; ++j) {
                __hip_bfloat16 h = __float2bfloat16(src[j*9 + tt]);
                v[j] = __builtin_bit_cast(short, h);
            }
            *(short8v*)(Wp + ((((size_t)(tt*48 + ot))*24 + ch) << 9) + lane8) = v;
        }
    } else {
        int n = (blk - CCH - 288)*256 + t;
        if (n < 324*324) { int i = n / 324, j = n - i*324; T1[(size_t)j*324 + i] = Wfc1[n]; }
        if (n < 81*324)  { int q = n / 324, j = n - q*324; T2[(size_t)j*81 + q]  = Wfc2[n]; }
    }
}

// ---------------- XP: x,y -> swizzled chunk images; fuse34 + ssim_wh fused --
__global__ __launch_bounds__(256) void k_xprep_f34(
    const float* __restrict__ x, const float* __restrict__ y,
    const float* __restrict__ wh3, const float* __restrict__ bh3,
    const float* __restrict__ wl2, const float* __restrict__ bl2,
    const float* __restrict__ W12, const float* __restrict__ b12,
    const float* __restrict__ Wl3, const float* __restrict__ bl3,
    __hip_bfloat16* __restrict__ xT2, __hip_bfloat16* __restrict__ yT2,
    float* __restrict__ f3, float* __restrict__ f4, float* __restrict__ Af)
{
    int b = blockIdx.x;
    int tid = threadIdx.x;
    __shared__ float ls[64][82];
    __shared__ float red[243][4];
    __shared__ float zz[10][81];
    __shared__ float tb[10][81];
    int q = tid / 81, p81 = tid - q*81;
    bool act = tid < 243;
    // zero row 81 of every chunk (pad rows 82..95 never read)
    for (int i = tid; i < 24*32; i += 256) {
        int ch = i >> 5, c = i & 31;
        xT2[(((size_t)b*24 + ch)*96 + 81)*32 + c] = __float2bfloat16(0.f);
    }
    if (tid < 2*32) {
        int ch = tid >> 5, c = tid & 31;
        yT2[(((size_t)b*2 + ch)*96 + 81)*32 + c] = __float2bfloat16(0.f);
    }
    float sx = 0.f;
    for (int c0 = 0; c0 < CCH; c0 += 64) {
        int ch0 = c0 >> 5;
        __syncthreads();
        for (int i = tid; i < 64*81; i += 256) {
            int c = i / 81, p = i - c*81;
            ls[c][p] = x[((size_t)b*CCH + c0 + c)*PP + p];
        }
        __syncthreads();
        for (int i = tid; i < 81*64; i += 256) {
            int p = i >> 6, c = i & 63;
            int ch = ch0 + (c >> 5), cc = c & 31;
            int s = cc >> 3, j = cc & 7;
            int slot = s ^ ((p >> 1) & 3);
            xT2[(((size_t)b*24 + ch)*96 + p)*32 + slot*8 + j] = __float2bfloat16(ls[c][p]);
        }
        if (act)
            for (int c = q; c < 64; c += 3)
                sx = fmaf(wh3[c0+c], ls[c][p81], sx);
    }
    __syncthreads();
    for (int i = tid; i < 64*81; i += 256) {
        int c = i / 81, p = i - c*81;
        ls[c][p] = y[((size_t)b*LCH + c)*PP + p];
    }
    __syncthreads();
    for (int i = tid; i < 81*64; i += 256) {
        int p = i >> 6, c = i & 63;
        int ch = c >> 5, cc = c & 31;
        int s = cc >> 3, j = cc & 7;
        int slot = s ^ ((p >> 1) & 3);
        yT2[(((size_t)b*2 + ch)*96 + p)*32 + slot*8 + j] = __float2bfloat16(ls[c][p]);
    }
    float sy = 0.f, s40 = 0.f, s41 = 0.f;
    if (act) {
        for (int c = q; c < 64; c += 3) {
            float v = ls[c][p81];
            sy  = fmaf(wl2[c], v, sy);
            s40 = fmaf(Wl3[c], v, s40);
            s41 = fmaf(Wl3[LCH+c], v, s41);
        }
        red[tid][0]=sx; red[tid][1]=sy; red[tid][2]=s40; red[tid][3]=s41;
    }
    __syncthreads();
    if (tid < 81) {
        float SX  = red[tid][0]+red[tid+81][0]+red[tid+162][0];
        float SY  = red[tid][1]+red[tid+81][1]+red[tid+162][1];
        float S40 = red[tid][2]+red[tid+81][2]+red[tid+162][2];
        float S41 = red[tid][3]+red[tid+81][3]+red[tid+162][3];
        float t3a = SX + bh3[0];
        float t3b = SY + bl2[0];
        float f30 = W12[0]*t3a + W12[1]*t3b + b12[0];
        float f31 = W12[2]*t3a + W12[3]*t3b + b12[1];
        float f40 = S40 + bl3[0];
        float f41 = S41 + bl3[1];
        f3[(b*2+0)*PP+tid] = f30; f3[(b*2+1)*PP+tid] = f31;
        f4[(b*2+0)*PP+tid] = f40; f4[(b*2+1)*PP+tid] = f41;
        zz[0][tid]=f30; zz[1][tid]=f40; zz[2][tid]=f30*f30; zz[3][tid]=f40*f40; zz[4][tid]=f30*f40;
        zz[5][tid]=f31; zz[6][tid]=f41; zz[7][tid]=f31*f31; zz[8][tid]=f41*f41; zz[9][tid]=f31*f41;
    }
    __syncthreads();
    for (int i = tid; i < 10*81; i += 256) {
        int f = i / 81, p = i - f*81;
        int yy = p/9, xx = p - yy*9;
        float s = 0.f;
        #pragma unroll
        for (int d = -3; d <= 3; ++d) {
            int j = xx + d;
            j = (j < 0) ? (-1-j) : ((j > 8) ? (17-j) : j);
            s += zz[f][yy*9+j];
        }
        tb[f][p] = s * (1.f/7.f);
    }
    __syncthreads();
    for (int i = tid; i < 10*81; i += 256) {
        int f = i / 81, p = i - f*81;
        int yy = p/9, xx = p - yy*9;
        float s = 0.f;
        #pragma unroll
        for (int d = -3; d <= 3; ++d) {
            int j = yy + d;
            j = (j < 0) ? (-1-j) : ((j > 8) ? (17-j) : j);
            s += tb[f][j*9+xx];
        }
        Af[((size_t)b*10 + f)*81 + p] = s * (1.f/7.f);
    }
}

// ---------------- S3: box-7 along batch, LDS-tiled --------------------------
__global__ __launch_bounds__(256) void k_ssim_b2(
    const float* __restrict__ A, float* __restrict__ U)
{
    int col0 = blockIdx.x * 32;
    int tid = threadIdx.x;
    __shared__ float lsb[256][33];
    for (int i = tid; i < 256*32; i += 256) {
        int j = i >> 5, cc = i & 31;
        int col = col0 + cc;
        lsb[j][cc] = (col < 810) ? A[(size_t)j*810 + col] : 0.f;
    }
    __syncthreads();
    for (int i = tid; i < 256*32; i += 256) {
        int b = i >> 5, cc = i & 31;
        float s = 0.f;
        #pragma unroll
        for (int d = -3; d <= 3; ++d) {
            int j = b + d;
            j = (j < 0) ? (-1-j) : ((j > 255) ? (511-j) : j);
            s += lsb[j][cc];
        }
        int col = col0 + cc;
        if (col < 810) U[(size_t)b*810 + col] = s * (1.f/7.f);
    }
}

// ---------------- F: ssim_comb + pool + fc1(gelu) + fc2(leaky) --------------
__global__ __launch_bounds__(128) void k_fc(
    const float* __restrict__ U, const float* __restrict__ f3,
    const float* __restrict__ f4, const float* __restrict__ wcc,
    const float* __restrict__ bcc,
    const float* __restrict__ wpool, const float* __restrict__ bpool,
    const float* __restrict__ T1, const float* __restrict__ bfc1,
    const float* __restrict__ T2, const float* __restrict__ bfc2,
    float* __restrict__ f22, float* __restrict__ ccs,
    float* __restrict__ xw)
{
    int b = blockIdx.x;
    int tid = threadIdx.x;
    __shared__ float xc[324];
    __shared__ float h1[324];
    __shared__ float pr[2][81], ps[2][81];
    const float cov = 343.f/342.f, C1c = 1e-4f, C2c = 9e-4f;
    for (int i = tid; i < 162; i += 128) {
        int k = i / 81, p = i - k*81;
        const float* u = U + (size_t)b*810 + (k*5)*81 + p;
        float ux = u[0], uy = u[81], uxx = u[162], uyy = u[243], uxy = u[324];
        float vx = cov*(uxx - ux*ux), vy = cov*(uyy - uy*uy), vxy = cov*(uxy - ux*uy);
        float S = ((2.f*ux*uy + C1c)*(2.f*vxy + C2c)) /
                  ((ux*ux + uy*uy + C1c)*(vx + vy + C2c));
        float a = f4[(b*2+k)*81+p] + S*f3[(b*2+k)*81+p];
        pr[k][p] = wcc[k]*a;
        ps[k][p] = wcc[k]*S;
    }
    __syncthreads();
    if (tid < 81) {
        float fv = pr[0][tid] + pr[1][tid] + bcc[0];
        float cv = ps[0][tid] + ps[1][tid] + bcc[0];
        f22[b*81+tid] = fv;
        ccs[b*81+tid] = cv;
        xc[tid] = fv; xc[243+tid] = fv;
    }
    __syncthreads();
    for (int i = tid; i < 162; i += 128) {
        int k = i / 81, p = i - k*81;
        int yy = p/9, xx = p - yy*9;
        float s = bpool[k];
        #pragma unroll
        for (int dy = -1; dy <= 1; ++dy)
            #pragma unroll
            for (int dx = -1; dx <= 1; ++dx) {
                int Y = yy+dy, X = xx+dx;
                if (Y >= 0 && Y < 9 && X >= 0 && X < 9)
                    s = fmaf(wpool[k*9 + (dy+1)*3 + (dx+1)], xc[Y*9+X], s);
            }
        xc[81+i] = s;
    }
    __syncthreads();
    for (int i = tid; i < 324; i += 128) {
        float s = bfc1[i];
        for (int j = 0; j < 324; ++j) s = fmaf(T1[(size_t)j*324 + i], xc[j], s);
        h1[i] = 0.5f*s*(1.f + erff(s*0.70710678118654752f));
    }
    __syncthreads();
    for (int qq = tid; qq < 81; qq += 128) {
        float s = bfc2[qq];
        for (int j = 0; j < 324; ++j) s = fmaf(T2[(size_t)j*81 + qq], h1[j], s);
        xw[b*81+qq] = (s > 0.f) ? s : 0.01f*s;
    }
}

// ---------------- K1 v10: fuse12 MFMA, direct-global B, no LDS, no barriers -
__global__ __launch_bounds__(256) void k_fuse12_mfma(
    const __hip_bfloat16* __restrict__ xT2,   // [B][24][96][32] swizzled image
    const __hip_bfloat16* __restrict__ yT2,   // [B][2][96][32]
    const __hip_bfloat16* __restrict__ Wh1p,
    const __hip_bfloat16* __restrict__ WAp,
    const __hip_bfloat16* __restrict__ WBp,
    const float* __restrict__ bh1, const float* __restrict__ beff,
    __hip_bfloat16* __restrict__ f1, __hip_bfloat16* __restrict__ f2)
{
    int oy = blockIdx.x;          // 0..7, o-extent 96; XCD = linear%8 = oy
    int b  = blockIdx.y;
    int tid = threadIdx.x;
    int w    = tid >> 6;          // 0..3
    int g    = w >> 1;            // 0 -> f1 (Wh1), 1 -> f2 (WA, WB)
    int nh   = w & 1;             // n-half
    int lane = tid & 63;
    int l15  = lane & 15;
    int kg   = lane >> 4;

    int spoff[3];
    #pragma unroll
    for (int nl = 0; nl < 3; ++nl) {
        int p = (nh*3 + nl)*16 + l15;
        int sp = (p < PP) ? p : 81;
        spoff[nl] = sp*32 + ((kg ^ ((sp >> 1) & 3)) << 3);
    }

    f32x4 acc[6][3];
    #pragma unroll
    for (int m = 0; m < 6; ++m)
        #pragma unroll
        for (int nl = 0; nl < 3; ++nl)
            acc[m][nl] = (f32x4){0.f,0.f,0.f,0.f};

    const __hip_bfloat16* xb = xT2 + (size_t)b*24*CHW;
    const __hip_bfloat16* yb = yT2 + (size_t)b*2*CHW;
    const __hip_bfloat16* Wsel = g ? WAp : Wh1p;
    int otb = oy*6;

    for (int ch = 0; ch < 24; ++ch) {
        const __hip_bfloat16* cb = xb + (size_t)ch*CHW;
        short8v bf[3];
        #pragma unroll
        for (int nl = 0; nl < 3; ++nl)
            bf[nl] = *(const short8v*)&cb[spoff[nl]];
        short8v a[6];
        #pragma unroll
        for (int m = 0; m < 6; ++m)
            a[m] = *(const short8v*)(Wsel + ((((size_t)(otb + m))*24 + ch) << 9) + (lane<<3));
        #pragma unroll
        for (int nl = 0; nl < 3; ++nl)
            #pragma unroll
            for (int m = 0; m < 6; ++m)
                acc[m][nl] = __builtin_amdgcn_mfma_f32_16x16x32_bf16(a[m], bf[nl], acc[m][nl], 0, 0, 0);
    }

    if (g == 1) {
        for (int ch2 = 0; ch2 < 2; ++ch2) {
            const __hip_bfloat16* cb = yb + (size_t)ch2*CHW;
            short8v bf[3];
            #pragma unroll
            for (int nl = 0; nl < 3; ++nl)
                bf[nl] = *(const short8v*)&cb[spoff[nl]];
            short8v a[6];
            #pragma unroll
            for (int m = 0; m < 6; ++m)
                a[m] = *(const short8v*)(WBp + ((((size_t)(otb + m))*2 + ch2) << 9) + (lane<<3));
            #pragma unroll
            for (int nl = 0; nl < 3; ++nl)
                #pragma unroll
                for (int m = 0; m < 6; ++m)
                    acc[m][nl] = __builtin_amdgcn_mfma_f32_16x16x32_bf16(a[m], bf[nl], acc[m][nl], 0, 0, 0);
        }
    }

    __hip_bfloat16* dst = g ? f2 : f1;
    const float* bias = g ? beff : bh1;
    #pragma unroll
    for (int m = 0; m < 6; ++m) {
        #pragma unroll
        for (int r = 0; r < 4; ++r) {
            int o = (otb + m)*16 + kg*4 + r;
            float bb = bias[o];
            #pragma unroll
            for (int nl = 0; nl < 3; ++nl) {
                int p = (nh*3 + nl)*16 + l15;
                if (p < PP)
                    dst[((size_t)b*CCH + o)*PP + p] = __float2bfloat16(acc[m][nl][r] + bb);
            }
        }
    }
}

// ---------------- FZ: cor sums + alpha/gamma + swizzled-image build ---------
__global__ __launch_bounds__(256) void k_finalize(
    const __hip_bfloat16* __restrict__ f1, const __hip_bfloat16* __restrict__ f2,
    const float* __restrict__ f22, const float* __restrict__ ccs,
    const float* __restrict__ xw,
    __hip_bfloat16* __restrict__ inb2)
{
    int b = blockIdx.x;
    int tid = threadIdx.x;
    __shared__ float red[243][5];
    __shared__ float sal[81], sga[81], scm[81];
    __shared__ float ls[64][82];
    // zero row 81 of every chunk
    for (int i = tid; i < 24*32; i += 256) {
        int ch = i >> 5, c = i & 31;
        inb2[(((size_t)b*24 + ch)*96 + 81)*32 + c] = __float2bfloat16(0.f);
    }
    bool act = tid < 243;
    float Sxx=0.f, Syy=0.f, Sxy=0.f, Sx=0.f, Sy=0.f;
    const __hip_bfloat16* A = f1 + (size_t)b*CCH*PP;
    const __hip_bfloat16* C = f2 + (size_t)b*CCH*PP;
    if (act) {
        for (int c0 = 0; c0 < CCH; c0 += 3) {
            float u = __bfloat162float(A[(size_t)c0*PP + tid]);
            float v = __bfloat162float(C[(size_t)c0*PP + tid]);
            Sxx = fmaf(u,u,Sxx); Syy = fmaf(v,v,Syy); Sxy = fmaf(u,v,Sxy);
            Sx += u; Sy += v;
        }
        red[tid][0]=Sxx; red[tid][1]=Syy; red[tid][2]=Sxy; red[tid][3]=Sx; red[tid][4]=Sy;
    }
    __syncthreads();
    if (tid < 81) {
        float xx = red[tid][0]+red[tid+81][0]+red[tid+162][0];
        float yy = red[tid][1]+red[tid+81][1]+red[tid+162][1];
        float xy = red[tid][2]+red[tid+81][2]+red[tid+162][2];
        float sx = red[tid][3]+red[tid+81][3]+red[tid+162][3];
        float sy = red[tid][4]+red[tid+81][4]+red[tid+162][4];
        float cor1 = xy / fmaxf(sqrtf(xx)*sqrtf(yy), 1e-8f);
        float al = 0.5f*(1.f - cor1);
        float sum21 = sx + al*sy;
        float n21 = sqrtf(fmaxf(xx + 2.f*al*xy + al*al*yy, 0.f));
        int t = b*81 + tid;
        float fv = f22[t];
        float cor2 = (fv * sum21) / fmaxf(n21 * 27.712812921102035f * fabsf(fv), 1e-8f);
        float be = 0.5f*(1.f - cor2 + ccs[t]);
        sal[tid] = al;
        sga[tid] = be * fv;
        scm[tid] = 1.f + xw[t];
    }
    for (int c0 = 0; c0 < CCH; c0 += 64) {
        int ch0 = c0 >> 5;
        __syncthreads();
        for (int i = tid; i < 64*81; i += 256) {
            int c = i / 81, p = i - c*81;
            size_t gidx = ((size_t)b*CCH + c0 + c)*PP + p;
            float u = __bfloat162float(f1[gidx]);
            float v = __bfloat162float(f2[gidx]);
            ls[c][p] = scm[p]*(u + sal[p]*v + sga[p]);
        }
        __syncthreads();
        for (int i = tid; i < 81*64; i += 256) {
            int p = i >> 6, c = i & 63;
            int ch = ch0 + (c >> 5), cc = c & 31;
            int s = cc >> 3, j = cc & 7;
            int slot = s ^ ((p >> 1) & 3);
            inb2[(((size_t)b*24 + ch)*96 + p)*32 + slot*8 + j] = __float2bfloat16(ls[c][p]);
        }
    }
}

// ---------------- KB v10: bconv MFMA, direct-global B, no LDS, no barriers --
__global__ __launch_bounds__(128) void k_bconv_mfma(
    const __hip_bfloat16* __restrict__ inb2,  // [B][24][96][32] swizzled image
    const __hip_bfloat16* __restrict__ Wp,    // packed [9][48][24][512]
    const float* __restrict__ bn_g, const float* __restrict__ bn_b,
    const float* __restrict__ bn_m, const float* __restrict__ bn_v,
    float* __restrict__ out)
{
    int oy = blockIdx.x;        // 0..7, o-extent 96; XCD = linear%8 = oy
    int b  = blockIdx.y;
    int tid = threadIdx.x;
    int w    = tid >> 6;        // 0..1 -> n-tiles {3w..3w+2}
    int lane = tid & 63;
    int l15  = lane & 15;
    int kg   = lane >> 4;

    int spoff[9][3];
    #pragma unroll
    for (int t = 0; t < 9; ++t) {
        int dy = t/3 - 1, dx = t%3 - 1;
        #pragma unroll
        for (int nl = 0; nl < 3; ++nl) {
            int p = (w*3 + nl)*16 + l15;
            int yy = p/9, xx = p - yy*9;
            int Y = yy + dy, X = xx + dx;
            bool ok = (p < PP) && (Y >= 0) && (Y < 9) && (X >= 0) && (X < 9);
            int sp = ok ? (Y*9 + X) : 81;
            spoff[t][nl] = sp*32 + ((kg ^ ((sp >> 1) & 3)) << 3);
        }
    }

    f32x4 acc[6][3];
    #pragma unroll
    for (int m = 0; m < 6; ++m)
        #pragma unroll
        for (int nl = 0; nl < 3; ++nl)
            acc[m][nl] = (f32x4){0.f,0.f,0.f,0.f};

    const __hip_bfloat16* img = inb2 + (size_t)b*24*CHW;
    int otb = oy*6;

    for (int ch = 0; ch < 24; ++ch) {
        const __hip_bfloat16* cb = img + (size_t)ch*CHW;
        #pragma unroll
        for (int t = 0; t < 9; ++t) {
            short8v bf[3];
            #pragma unroll
            for (int nl = 0; nl < 3; ++nl)
                bf[nl] = *(const short8v*)&cb[spoff[t][nl]];
            short8v a[6];
            #pragma unroll
            for (int m = 0; m < 6; ++m)
                a[m] = *(const short8v*)(Wp + (((size_t)(t*48 + otb + m)*24 + ch) << 9) + (lane<<3));
            #pragma unroll
            for (int nl = 0; nl < 3; ++nl)
                #pragma unroll
                for (int m = 0; m < 6; ++m)
                    acc[m][nl] = __builtin_amdgcn_mfma_f32_16x16x32_bf16(a[m], bf[nl], acc[m][nl], 0, 0, 0);
        }
    }

    #pragma unroll
    for (int m = 0; m < 6; ++m) {
        #pragma unroll
        for (int r = 0; r < 4; ++r) {
            int o = (otb + m)*16 + kg*4 + r;
            float sc = bn_g[o] * rsqrtf(bn_v[o] + 1e-5f);
            float mn = bn_m[o], bt = bn_b[o];
            #pragma unroll
            for (int nl = 0; nl < 3; ++nl) {
                int p = (w*3 + nl)*16 + l15;
                if (p < PP) {
                    float v = (acc[m][nl][r] - mn) * sc + bt;
                    out[((size_t)b*CCH + o)*PP + p] = (v > 0.f) ? v : 0.01f*v;
                }
            }
        }
    }
}

extern "C" void kernel_launch(void* const* d_in, const int* in_sizes, int n_in,
                              void* d_out, int out_size, void* d_ws, size_t ws_size,
                              hipStream_t stream)
{
    (void)in_sizes; (void)n_in; (void)out_size; (void)ws_size;
    const float* x    = (const float*)d_in[0];
    const float* y    = (const float*)d_in[1];
    const float* Wh1  = (const float*)d_in[2];
    const float* bh1  = (const float*)d_in[3];
    const float* W11  = (const float*)d_in[4];
    const float* b11  = (const float*)d_in[5];
    const float* Wh2  = (const float*)d_in[6];
    const float* bh2  = (const float*)d_in[7];
    const float* Wl1  = (const float*)d_in[8];
    const float* bl1  = (const float*)d_in[9];
    const float* wh3  = (const float*)d_in[10];
    const float* bh3  = (const float*)d_in[11];
    const float* wl2  = (const float*)d_in[12];
    const float* bl2  = (const float*)d_in[13];
    const float* W12  = (const float*)d_in[14];
    const float* b12  = (const float*)d_in[15];
    const float* Wl3  = (const float*)d_in[16];
    const float* bl3  = (const float*)d_in[17];
    const float* wcc  = (const float*)d_in[18];
    const float* bcc  = (const float*)d_in[19];
    const float* wpool= (const float*)d_in[20];
    const float* bpool= (const float*)d_in[21];
    const float* Wfc1 = (const float*)d_in[22];
    const float* bfc1 = (const float*)d_in[23];
    const float* Wfc2 = (const float*)d_in[24];
    const float* bfc2 = (const float*)d_in[25];
    const float* Wb   = (const float*)d_in[26];
    const float* bng  = (const float*)d_in[27];
    const float* bnb  = (const float*)d_in[28];
    const float* bnm  = (const float*)d_in[29];
    const float* bnv  = (const float*)d_in[30];
    float* out = (float*)d_out;
    float* ws = (float*)d_ws;

    size_t off = 0;
    float* beff  = ws + off; off += CCH;
    float* f3    = ws + off; off += BATCH*2*PP;
    float* f4    = ws + off; off += BATCH*2*PP;
    float* Af    = ws + off; off += BATCH*10*PP;
    float* Uf    = ws + off; off += BATCH*10*PP;
    float* f22   = ws + off; off += BATCH*PP;
    float* ccs   = ws + off; off += BATCH*PP;
    float* xw    = ws + off; off += BATCH*PP;
    float* T1    = ws + off; off += 324*324;
    float* T2    = ws + off; off += 324*81;
    off = (off + 3) & ~(size_t)3;   // 16B-align bf16 region
    __hip_bfloat16* Wh1p = (__hip_bfloat16*)(ws + off); off += (size_t)48*24*512/2;
    __hip_bfloat16* WAp  = (__hip_bfloat16*)(ws + off); off += (size_t)48*24*512/2;
    __hip_bfloat16* WBp  = (__hip_bfloat16*)(ws + off); off += (size_t)48*2*512/2;
    __hip_bfloat16* yT2  = (__hip_bfloat16*)(ws + off); off += (size_t)BATCH*2*CHW/2;
    __hip_bfloat16* f1b  = (__hip_bfloat16*)(ws + off); off += (size_t)BATCH*CCH*PP/2;
    __hip_bfloat16* f2b  = (__hip_bfloat16*)(ws + off); off += (size_t)BATCH*CCH*PP/2;
    off = (off + 3) & ~(size_t)3;
    __hip_bfloat16* inb2 = (__hip_bfloat16*)(ws + off); off += (size_t)BATCH*24*CHW/2;
    __hip_bfloat16* Wp   = (__hip_bfloat16*)(ws + off); off += (size_t)9*48*24*512/2;
    // xT2 aliases inb2: fuse12 consumes xT2 before k_finalize overwrites it
    __hip_bfloat16* xT2 = inb2;

    k_prep<<<dim3(CCH + 288 + 411), dim3(256), 0, stream>>>(
        W11, Wh2, Wl1, bh2, bl1, b11, Wh1, Wb, Wfc1, Wfc2,
        WAp, WBp, Wh1p, beff, Wp, T1, T2);
    k_xprep_f34<<<dim3(BATCH), dim3(256), 0, stream>>>(x, y, wh3, bh3, wl2, bl2, W12, b12, Wl3, bl3, xT2, yT2, f3, f4, Af);
    k_ssim_b2<<<dim3(26), dim3(256), 0, stream>>>(Af, Uf);
    k_fc<<<dim3(BATCH), dim3(128), 0, stream>>>(Uf, f3, f4, wcc, bcc, wpool, bpool, T1, bfc1, T2, bfc2, f22, ccs, xw);
    k_fuse12_mfma<<<dim3(8, BATCH), dim3(256), 0, stream>>>(xT2, yT2, Wh1p, WAp, WBp, bh1, beff, f1b, f2b);
    k_finalize<<<dim3(BATCH), dim3(256), 0, stream>>>(f1b, f2b, f22, ccs, xw, inb2);
    k_bconv_mfma<<<dim3(8, BATCH), dim3(128), 0, stream>>>(inb2, Wp, bng, bnb, bnm, bnv, out);
}

// Round 15
// 730.285 us; speedup vs baseline: 1.2451x; 1.2451x over previous
//
#include <hip/hip_runtime.h>
#include <hip/hip_bf16.h>
#include <math.h>

#define BATCH 256
#define CCH 768
#define LCH 64
#define PP 81
#define CHW 3072   // elems per chunk image: 96 rows x 32 ch

typedef __attribute__((ext_vector_type(8))) short short8v;
typedef __attribute__((ext_vector_type(4))) float f32x4;

#define GLL16(gp, lp) __builtin_amdgcn_global_load_lds( \
    (const __attribute__((address_space(1))) void*)(gp), \
    (__attribute__((address_space(3))) void*)(lp), 16, 0, 0)

// ---------------- P: merged weight prep (compose + wprep + fcprep) ----------
__global__ __launch_bounds__(256) void k_prep(
    const float* __restrict__ W11, const float* __restrict__ Wh2,
    const float* __restrict__ Wl1, const float* __restrict__ bh2,
    const float* __restrict__ bl1, const float* __restrict__ b11,
    const float* __restrict__ Wh1, const float* __restrict__ Wb,
    const float* __restrict__ Wfc1, const float* __restrict__ Wfc2,
    __hip_bfloat16* __restrict__ WAp, __hip_bfloat16* __restrict__ WBp,
    __hip_bfloat16* __restrict__ Wh1p, float* __restrict__ beff,
    __hip_bfloat16* __restrict__ Wp,
    float* __restrict__ T1, float* __restrict__ T2)
{
    int blk = blockIdx.x;
    int t = threadIdx.x;
    if (blk < CCH) {
        int o = blk;
        int ot = o >> 4, l15o = o & 15;
        const float* w11row = W11 + (size_t)o * CCH;
        for (int c = t; c < CCH; c += 256) {
            float s = 0.f;
            for (int k = 0; k < 512; ++k) s = fmaf(w11row[k], Wh2[(size_t)k*CCH + c], s);
            int ch = c >> 5, kg = (c >> 3) & 3, j = c & 7;
            size_t idx = (((size_t)ot*24 + ch) << 9) + (size_t)(kg*16 + l15o)*8 + j;
            WAp[idx]  = __float2bfloat16(s);
            Wh1p[idx] = __float2bfloat16(Wh1[(size_t)o*CCH + c]);
        }
        if (t < LCH) {
            float s = 0.f;
            for (int k = 0; k < 256; ++k) s = fmaf(w11row[512+k], Wl1[k*LCH + t], s);
            int ch = t >> 5, kg = (t >> 3) & 3, j = t & 7;
            size_t idx = (((size_t)ot*2 + ch) << 9) + (size_t)(kg*16 + l15o)*8 + j;
            WBp[idx] = __float2bfloat16(s);
        }
        if (t == 0) {
            float s = b11[o];
            for (int k = 0; k < 512; ++k) s = fmaf(w11row[k], bh2[k], s);
            for (int k = 0; k < 256; ++k) s = fmaf(w11row[512+k], bl1[k], s);
            beff[o] = s;
        }
    } else if (blk < CCH + 288) {
        int id = blk - CCH;
        int ot = id / 6;
        int i  = (id - ot*6)*256 + t;
        int oi = i / 96, c8 = i - oi*96;
        const float* src = Wb + ((size_t)(ot*16 + oi)*CCH + c8*8)*9;
        int ch = c8 >> 2;
        int lane8 = (((c8 & 3)*16) + oi)*8;
        #pragma unroll
        for (int tt = 0; tt < 9; ++tt) {
            short8v v;
            #pragma unroll
            for (int j = 0; j < 8; ++j) {
                __hip_bfloat16 h = __float2bfloat16(src[j*9 + tt]);
                v[j] = __builtin_bit_cast(short, h);
            }
            *(short8v*)(Wp + ((((size_t)(tt*48 + ot))*24 + ch) << 9) + lane8) = v;
        }
    } else {
        int n = (blk - CCH - 288)*256 + t;
        if (n < 324*324) { int i = n / 324, j = n - i*324; T1[(size_t)j*324 + i] = Wfc1[n]; }
        if (n < 81*324)  { int q = n / 324, j = n - q*324; T2[(size_t)j*81 + q]  = Wfc2[n]; }
    }
}

// ---------------- XP: x,y -> swizzled chunk images; fuse34 + ssim_wh fused --
__global__ __launch_bounds__(256) void k_xprep_f34(
    const float* __restrict__ x, const float* __restrict__ y,
    const float* __restrict__ wh3, const float* __restrict__ bh3,
    const float* __restrict__ wl2, const float* __restrict__ bl2,
    const float* __restrict__ W12, const float* __restrict__ b12,
    const float* __restrict__ Wl3, const float* __restrict__ bl3,
    __hip_bfloat16* __restrict__ xT2, __hip_bfloat16* __restrict__ yT2,
    float* __restrict__ f3, float* __restrict__ f4, float* __restrict__ Af)
{
    int b = blockIdx.x;
    int tid = threadIdx.x;
    __shared__ float ls[64][82];
    __shared__ float red[243][4];
    __shared__ float zz[10][81];
    __shared__ float tb[10][81];
    int q = tid / 81, p81 = tid - q*81;
    bool act = tid < 243;
    // zero row 81 of every chunk (pad rows 82..95 never read)
    for (int i = tid; i < 24*32; i += 256) {
        int ch = i >> 5, c = i & 31;
        xT2[(((size_t)b*24 + ch)*96 + 81)*32 + c] = __float2bfloat16(0.f);
    }
    if (tid < 2*32) {
        int ch = tid >> 5, c = tid & 31;
        yT2[(((size_t)b*2 + ch)*96 + 81)*32 + c] = __float2bfloat16(0.f);
    }
    float sx = 0.f;
    for (int c0 = 0; c0 < CCH; c0 += 64) {
        int ch0 = c0 >> 5;
        __syncthreads();
        for (int i = tid; i < 64*81; i += 256) {
            int c = i / 81, p = i - c*81;
            ls[c][p] = x[((size_t)b*CCH + c0 + c)*PP + p];
        }
        __syncthreads();
        for (int i = tid; i < 81*64; i += 256) {
            int p = i >> 6, c = i & 63;
            int ch = ch0 + (c >> 5), cc = c & 31;
            int s = cc >> 3, j = cc & 7;
            int slot = s ^ ((p >> 1) & 3);
            xT2[(((size_t)b*24 + ch)*96 + p)*32 + slot*8 + j] = __float2bfloat16(ls[c][p]);
        }
        if (act)
            for (int c = q; c < 64; c += 3)
                sx = fmaf(wh3[c0+c], ls[c][p81], sx);
    }
    __syncthreads();
    for (int i = tid; i < 64*81; i += 256) {
        int c = i / 81, p = i - c*81;
        ls[c][p] = y[((size_t)b*LCH + c)*PP + p];
    }
    __syncthreads();
    for (int i = tid; i < 81*64; i += 256) {
        int p = i >> 6, c = i & 63;
        int ch = c >> 5, cc = c & 31;
        int s = cc >> 3, j = cc & 7;
        int slot = s ^ ((p >> 1) & 3);
        yT2[(((size_t)b*2 + ch)*96 + p)*32 + slot*8 + j] = __float2bfloat16(ls[c][p]);
    }
    float sy = 0.f, s40 = 0.f, s41 = 0.f;
    if (act) {
        for (int c = q; c < 64; c += 3) {
            float v = ls[c][p81];
            sy  = fmaf(wl2[c], v, sy);
            s40 = fmaf(Wl3[c], v, s40);
            s41 = fmaf(Wl3[LCH+c], v, s41);
        }
        red[tid][0]=sx; red[tid][1]=sy; red[tid][2]=s40; red[tid][3]=s41;
    }
    __syncthreads();
    if (tid < 81) {
        float SX  = red[tid][0]+red[tid+81][0]+red[tid+162][0];
        float SY  = red[tid][1]+red[tid+81][1]+red[tid+162][1];
        float S40 = red[tid][2]+red[tid+81][2]+red[tid+162][2];
        float S41 = red[tid][3]+red[tid+81][3]+red[tid+162][3];
        float t3a = SX + bh3[0];
        float t3b = SY + bl2[0];
        float f30 = W12[0]*t3a + W12[1]*t3b + b12[0];
        float f31 = W12[2]*t3a + W12[3]*t3b + b12[1];
        float f40 = S40 + bl3[0];
        float f41 = S41 + bl3[1];
        f3[(b*2+0)*PP+tid] = f30; f3[(b*2+1)*PP+tid] = f31;
        f4[(b*2+0)*PP+tid] = f40; f4[(b*2+1)*PP+tid] = f41;
        zz[0][tid]=f30; zz[1][tid]=f40; zz[2][tid]=f30*f30; zz[3][tid]=f40*f40; zz[4][tid]=f30*f40;
        zz[5][tid]=f31; zz[6][tid]=f41; zz[7][tid]=f31*f31; zz[8][tid]=f41*f41; zz[9][tid]=f31*f41;
    }
    __syncthreads();
    for (int i = tid; i < 10*81; i += 256) {
        int f = i / 81, p = i - f*81;
        int yy = p/9, xx = p - yy*9;
        float s = 0.f;
        #pragma unroll
        for (int d = -3; d <= 3; ++d) {
            int j = xx + d;
            j = (j < 0) ? (-1-j) : ((j > 8) ? (17-j) : j);
            s += zz[f][yy*9+j];
        }
        tb[f][p] = s * (1.f/7.f);
    }
    __syncthreads();
    for (int i = tid; i < 10*81; i += 256) {
        int f = i / 81, p = i - f*81;
        int yy = p/9, xx = p - yy*9;
        float s = 0.f;
        #pragma unroll
        for (int d = -3; d <= 3; ++d) {
            int j = yy + d;
            j = (j < 0) ? (-1-j) : ((j > 8) ? (17-j) : j);
            s += tb[f][j*9+xx];
        }
        Af[((size_t)b*10 + f)*81 + p] = s * (1.f/7.f);
    }
}

// ---------------- S3: box-7 along batch, LDS-tiled --------------------------
__global__ __launch_bounds__(256) void k_ssim_b2(
    const float* __restrict__ A, float* __restrict__ U)
{
    int col0 = blockIdx.x * 32;
    int tid = threadIdx.x;
    __shared__ float lsb[256][33];
    for (int i = tid; i < 256*32; i += 256) {
        int j = i >> 5, cc = i & 31;
        int col = col0 + cc;
        lsb[j][cc] = (col < 810) ? A[(size_t)j*810 + col] : 0.f;
    }
    __syncthreads();
    for (int i = tid; i < 256*32; i += 256) {
        int b = i >> 5, cc = i & 31;
        float s = 0.f;
        #pragma unroll
        for (int d = -3; d <= 3; ++d) {
            int j = b + d;
            j = (j < 0) ? (-1-j) : ((j > 255) ? (511-j) : j);
            s += lsb[j][cc];
        }
        int col = col0 + cc;
        if (col < 810) U[(size_t)b*810 + col] = s * (1.f/7.f);
    }
}

// ---------------- F: ssim_comb + pool + fc1(gelu) + fc2(leaky) --------------
__global__ __launch_bounds__(128) void k_fc(
    const float* __restrict__ U, const float* __restrict__ f3,
    const float* __restrict__ f4, const float* __restrict__ wcc,
    const float* __restrict__ bcc,
    const float* __restrict__ wpool, const float* __restrict__ bpool,
    const float* __restrict__ T1, const float* __restrict__ bfc1,
    const float* __restrict__ T2, const float* __restrict__ bfc2,
    float* __restrict__ f22, float* __restrict__ ccs,
    float* __restrict__ xw)
{
    int b = blockIdx.x;
    int tid = threadIdx.x;
    __shared__ float xc[324];
    __shared__ float h1[324];
    __shared__ float pr[2][81], ps[2][81];
    const float cov = 343.f/342.f, C1c = 1e-4f, C2c = 9e-4f;
    for (int i = tid; i < 162; i += 128) {
        int k = i / 81, p = i - k*81;
        const float* u = U + (size_t)b*810 + (k*5)*81 + p;
        float ux = u[0], uy = u[81], uxx = u[162], uyy = u[243], uxy = u[324];
        float vx = cov*(uxx - ux*ux), vy = cov*(uyy - uy*uy), vxy = cov*(uxy - ux*uy);
        float S = ((2.f*ux*uy + C1c)*(2.f*vxy + C2c)) /
                  ((ux*ux + uy*uy + C1c)*(vx + vy + C2c));
        float a = f4[(b*2+k)*81+p] + S*f3[(b*2+k)*81+p];
        pr[k][p] = wcc[k]*a;
        ps[k][p] = wcc[k]*S;
    }
    __syncthreads();
    if (tid < 81) {
        float fv = pr[0][tid] + pr[1][tid] + bcc[0];
        float cv = ps[0][tid] + ps[1][tid] + bcc[0];
        f22[b*81+tid] = fv;
        ccs[b*81+tid] = cv;
        xc[tid] = fv; xc[243+tid] = fv;
    }
    __syncthreads();
    for (int i = tid; i < 162; i += 128) {
        int k = i / 81, p = i - k*81;
        int yy = p/9, xx = p - yy*9;
        float s = bpool[k];
        #pragma unroll
        for (int dy = -1; dy <= 1; ++dy)
            #pragma unroll
            for (int dx = -1; dx <= 1; ++dx) {
                int Y = yy+dy, X = xx+dx;
                if (Y >= 0 && Y < 9 && X >= 0 && X < 9)
                    s = fmaf(wpool[k*9 + (dy+1)*3 + (dx+1)], xc[Y*9+X], s);
            }
        xc[81+i] = s;
    }
    __syncthreads();
    for (int i = tid; i < 324; i += 128) {
        float s = bfc1[i];
        for (int j = 0; j < 324; ++j) s = fmaf(T1[(size_t)j*324 + i], xc[j], s);
        h1[i] = 0.5f*s*(1.f + erff(s*0.70710678118654752f));
    }
    __syncthreads();
    for (int qq = tid; qq < 81; qq += 128) {
        float s = bfc2[qq];
        for (int j = 0; j < 324; ++j) s = fmaf(T2[(size_t)j*81 + qq], h1[j], s);
        xw[b*81+qq] = (s > 0.f) ? s : 0.01f*s;
    }
}

// ---------------- K1 v10: fuse12 MFMA, direct-global B, no LDS, no barriers -
__global__ __launch_bounds__(256) void k_fuse12_mfma(
    const __hip_bfloat16* __restrict__ xT2,   // [B][24][96][32] swizzled image
    const __hip_bfloat16* __restrict__ yT2,   // [B][2][96][32]
    const __hip_bfloat16* __restrict__ Wh1p,
    const __hip_bfloat16* __restrict__ WAp,
    const __hip_bfloat16* __restrict__ WBp,
    const float* __restrict__ bh1, const float* __restrict__ beff,
    __hip_bfloat16* __restrict__ f1, __hip_bfloat16* __restrict__ f2)
{
    int oy = blockIdx.x;          // 0..7, o-extent 96; XCD = linear%8 = oy
    int b  = blockIdx.y;
    int tid = threadIdx.x;
    int w    = tid >> 6;          // 0..3
    int g    = w >> 1;            // 0 -> f1 (Wh1), 1 -> f2 (WA, WB)
    int nh   = w & 1;             // n-half
    int lane = tid & 63;
    int l15  = lane & 15;
    int kg   = lane >> 4;

    int spoff[3];
    #pragma unroll
    for (int nl = 0; nl < 3; ++nl) {
        int p = (nh*3 + nl)*16 + l15;
        int sp = (p < PP) ? p : 81;
        spoff[nl] = sp*32 + ((kg ^ ((sp >> 1) & 3)) << 3);
    }

    f32x4 acc[6][3];
    #pragma unroll
    for (int m = 0; m < 6; ++m)
        #pragma unroll
        for (int nl = 0; nl < 3; ++nl)
            acc[m][nl] = (f32x4){0.f,0.f,0.f,0.f};

    const __hip_bfloat16* xb = xT2 + (size_t)b*24*CHW;
    const __hip_bfloat16* yb = yT2 + (size_t)b*2*CHW;
    const __hip_bfloat16* Wsel = g ? WAp : Wh1p;
    int otb = oy*6;

    for (int ch = 0; ch < 24; ++ch) {
        const __hip_bfloat16* cb = xb + (size_t)ch*CHW;
        short8v bf[3];
        #pragma unroll
        for (int nl = 0; nl < 3; ++nl)
            bf[nl] = *(const short8v*)&cb[spoff[nl]];
        short8v a[6];
        #pragma unroll
        for (int m = 0; m < 6; ++m)
            a[m] = *(const short8v*)(Wsel + ((((size_t)(otb + m))*24 + ch) << 9) + (lane<<3));
        #pragma unroll
        for (int nl = 0; nl < 3; ++nl)
            #pragma unroll
            for (int m = 0; m < 6; ++m)
                acc[m][nl] = __builtin_amdgcn_mfma_f32_16x16x32_bf16(a[m], bf[nl], acc[m][nl], 0, 0, 0);
    }

    if (g == 1) {
        for (int ch2 = 0; ch2 < 2; ++ch2) {
            const __hip_bfloat16* cb = yb + (size_t)ch2*CHW;
            short8v bf[3];
            #pragma unroll
            for (int nl = 0; nl < 3; ++nl)
                bf[nl] = *(const short8v*)&cb[spoff[nl]];
            short8v a[6];
            #pragma unroll
            for (int m = 0; m < 6; ++m)
                a[m] = *(const short8v*)(WBp + ((((size_t)(otb + m))*2 + ch2) << 9) + (lane<<3));
            #pragma unroll
            for (int nl = 0; nl < 3; ++nl)
                #pragma unroll
                for (int m = 0; m < 6; ++m)
                    acc[m][nl] = __builtin_amdgcn_mfma_f32_16x16x32_bf16(a[m], bf[nl], acc[m][nl], 0, 0, 0);
        }
    }

    __hip_bfloat16* dst = g ? f2 : f1;
    const float* bias = g ? beff : bh1;
    #pragma unroll
    for (int m = 0; m < 6; ++m) {
        #pragma unroll
        for (int r = 0; r < 4; ++r) {
            int o = (otb + m)*16 + kg*4 + r;
            float bb = bias[o];
            #pragma unroll
            for (int nl = 0; nl < 3; ++nl) {
                int p = (nh*3 + nl)*16 + l15;
                if (p < PP)
                    dst[((size_t)b*CCH + o)*PP + p] = __float2bfloat16(acc[m][nl][r] + bb);
            }
        }
    }
}

// ---------------- FZ: cor sums + alpha/gamma + swizzled-image build ---------
__global__ __launch_bounds__(256) void k_finalize(
    const __hip_bfloat16* __restrict__ f1, const __hip_bfloat16* __restrict__ f2,
    const float* __restrict__ f22, const float* __restrict__ ccs,
    const float* __restrict__ xw,
    __hip_bfloat16* __restrict__ inb2)
{
    int b = blockIdx.x;
    int tid = threadIdx.x;
    __shared__ float red[243][5];
    __shared__ float sal[81], sga[81], scm[81];
    __shared__ float ls[64][82];
    // zero row 81 of every chunk
    for (int i = tid; i < 24*32; i += 256) {
        int ch = i >> 5, c = i & 31;
        inb2[(((size_t)b*24 + ch)*96 + 81)*32 + c] = __float2bfloat16(0.f);
    }
    bool act = tid < 243;
    float Sxx=0.f, Syy=0.f, Sxy=0.f, Sx=0.f, Sy=0.f;
    const __hip_bfloat16* A = f1 + (size_t)b*CCH*PP;
    const __hip_bfloat16* C = f2 + (size_t)b*CCH*PP;
    if (act) {
        for (int c0 = 0; c0 < CCH; c0 += 3) {
            float u = __bfloat162float(A[(size_t)c0*PP + tid]);
            float v = __bfloat162float(C[(size_t)c0*PP + tid]);
            Sxx = fmaf(u,u,Sxx); Syy = fmaf(v,v,Syy); Sxy = fmaf(u,v,Sxy);
            Sx += u; Sy += v;
        }
        red[tid][0]=Sxx; red[tid][1]=Syy; red[tid][2]=Sxy; red[tid][3]=Sx; red[tid][4]=Sy;
    }
    __syncthreads();
    if (tid < 81) {
        float xx = red[tid][0]+red[tid+81][0]+red[tid+162][0];
        float yy = red[tid][1]+red[tid+81][1]+red[tid+162][1];
        float xy = red[tid][2]+red[tid+81][2]+red[tid+162][2];
        float sx = red[tid][3]+red[tid+81][3]+red[tid+162][3];
        float sy = red[tid][4]+red[tid+81][4]+red[tid+162][4];
        float cor1 = xy / fmaxf(sqrtf(xx)*sqrtf(yy), 1e-8f);
        float al = 0.5f*(1.f - cor1);
        float sum21 = sx + al*sy;
        float n21 = sqrtf(fmaxf(xx + 2.f*al*xy + al*al*yy, 0.f));
        int t = b*81 + tid;
        float fv = f22[t];
        float cor2 = (fv * sum21) / fmaxf(n21 * 27.712812921102035f * fabsf(fv), 1e-8f);
        float be = 0.5f*(1.f - cor2 + ccs[t]);
        sal[tid] = al;
        sga[tid] = be * fv;
        scm[tid] = 1.f + xw[t];
    }
    for (int c0 = 0; c0 < CCH; c0 += 64) {
        int ch0 = c0 >> 5;
        __syncthreads();
        for (int i = tid; i < 64*81; i += 256) {
            int c = i / 81, p = i - c*81;
            size_t gidx = ((size_t)b*CCH + c0 + c)*PP + p;
            float u = __bfloat162float(f1[gidx]);
            float v = __bfloat162float(f2[gidx]);
            ls[c][p] = scm[p]*(u + sal[p]*v + sga[p]);
        }
        __syncthreads();
        for (int i = tid; i < 81*64; i += 256) {
            int p = i >> 6, c = i & 63;
            int ch = ch0 + (c >> 5), cc = c & 31;
            int s = cc >> 3, j = cc & 7;
            int slot = s ^ ((p >> 1) & 3);
            inb2[(((size_t)b*24 + ch)*96 + p)*32 + slot*8 + j] = __float2bfloat16(ls[c][p]);
        }
    }
}

// ---------------- KB v11: bconv MFMA, 2 batches/block, 6-chunk groups -------
__global__ __launch_bounds__(256, 2) void k_bconv_mfma(
    const __hip_bfloat16* __restrict__ inb2,  // [B][24][96][32] swizzled image
    const __hip_bfloat16* __restrict__ Wp,    // packed [9][48][24][512]
    const float* __restrict__ bn_g, const float* __restrict__ bn_b,
    const float* __restrict__ bn_m, const float* __restrict__ bn_v,
    float* __restrict__ out)
{
    int oy = blockIdx.x;        // 0..7, o-extent 96; XCD = linear%8 = oy
    int b0 = blockIdx.y * 2;
    int tid = threadIdx.x;
    int w    = tid >> 6;        // 0..3
    int bi   = w >> 1;          // batch within pair
    int nh   = w & 1;           // n-half -> n-tiles {3*nh..3*nh+2}
    int lane = tid & 63;
    int l15  = lane & 15;
    int kg   = lane >> 4;

    __shared__ __align__(16) __hip_bfloat16 ls[12*CHW];  // [2 b][6 chunks] = 72 KB

    int spoff[9][3];
    #pragma unroll
    for (int t = 0; t < 9; ++t) {
        int dy = t/3 - 1, dx = t%3 - 1;
        #pragma unroll
        for (int nl = 0; nl < 3; ++nl) {
            int p = (nh*3 + nl)*16 + l15;
            int yy = p/9, xx = p - yy*9;
            int Y = yy + dy, X = xx + dx;
            bool ok = (p < PP) && (Y >= 0) && (Y < 9) && (X >= 0) && (X < 9);
            int sp = ok ? (Y*9 + X) : 81;
            spoff[t][nl] = sp*32 + ((kg ^ ((sp >> 1) & 3)) << 3);
        }
    }

    f32x4 acc[6][3];
    #pragma unroll
    for (int m = 0; m < 6; ++m)
        #pragma unroll
        for (int nl = 0; nl < 3; ++nl)
            acc[m][nl] = (f32x4){0.f,0.f,0.f,0.f};

    const __hip_bfloat16* img0 = inb2 + (size_t)(b0    )*24*CHW;
    const __hip_bfloat16* img1 = inb2 + (size_t)(b0 + 1)*24*CHW;
    int otb = oy*6;

    for (int grp = 0; grp < 4; ++grp) {
        __syncthreads();
        // stage 6 chunks x 2 batches = 72 slabs of 1KB; 18 per wave
        #pragma unroll
        for (int k = 0; k < 18; ++k) {
            int it = w + 4*k;                 // 0..71
            int bb = it / 36;
            int r  = it - bb*36;
            int cc = r / 6, sub = r - cc*6;
            const __hip_bfloat16* src =
                (bb ? img1 : img0) + (size_t)(grp*6 + cc)*CHW + sub*512;
            GLL16(src + lane*8, &ls[(size_t)(bb*6 + cc)*CHW + sub*512]);
        }
        __syncthreads();
        for (int cc = 0; cc < 6; ++cc) {
            int ch = grp*6 + cc;
            const __hip_bfloat16* lb = &ls[(size_t)(bi*6 + cc)*CHW];
            #pragma unroll
            for (int t = 0; t < 9; ++t) {
                short8v a[6];
                #pragma unroll
                for (int m = 0; m < 6; ++m)
                    a[m] = *(const short8v*)(Wp + (((size_t)(t*48 + otb + m)*24 + ch) << 9) + (lane<<3));
                #pragma unroll
                for (int nl = 0; nl < 3; ++nl) {
                    short8v bf = *(const short8v*)&lb[spoff[t][nl]];
                    #pragma unroll
                    for (int m = 0; m < 6; ++m)
                        acc[m][nl] = __builtin_amdgcn_mfma_f32_16x16x32_bf16(a[m], bf, acc[m][nl], 0, 0, 0);
                }
            }
        }
    }

    int b = b0 + bi;
    #pragma unroll
    for (int m = 0; m < 6; ++m) {
        #pragma unroll
        for (int r = 0; r < 4; ++r) {
            int o = (otb + m)*16 + kg*4 + r;
            float sc = bn_g[o] * rsqrtf(bn_v[o] + 1e-5f);
            float mn = bn_m[o], bt = bn_b[o];
            #pragma unroll
            for (int nl = 0; nl < 3; ++nl) {
                int p = (nh*3 + nl)*16 + l15;
                if (p < PP) {
                    float v = (acc[m][nl][r] - mn) * sc + bt;
                    out[((size_t)b*CCH + o)*PP + p] = (v > 0.f) ? v : 0.01f*v;
                }
            }
        }
    }
}

extern "C" void kernel_launch(void* const* d_in, const int* in_sizes, int n_in,
                              void* d_out, int out_size, void* d_ws, size_t ws_size,
                              hipStream_t stream)
{
    (void)in_sizes; (void)n_in; (void)out_size; (void)ws_size;
    const float* x    = (const float*)d_in[0];
    const float* y    = (const float*)d_in[1];
    const float* Wh1  = (const float*)d_in[2];
    const float* bh1  = (const float*)d_in[3];
    const float* W11  = (const float*)d_in[4];
    const float* b11  = (const float*)d_in[5];
    const float* Wh2  = (const float*)d_in[6];
    const float* bh2  = (const float*)d_in[7];
    const float* Wl1  = (const float*)d_in[8];
    const float* bl1  = (const float*)d_in[9];
    const float* wh3  = (const float*)d_in[10];
    const float* bh3  = (const float*)d_in[11];
    const float* wl2  = (const float*)d_in[12];
    const float* bl2  = (const float*)d_in[13];
    const float* W12  = (const float*)d_in[14];
    const float* b12  = (const float*)d_in[15];
    const float* Wl3  = (const float*)d_in[16];
    const float* bl3  = (const float*)d_in[17];
    const float* wcc  = (const float*)d_in[18];
    const float* bcc  = (const float*)d_in[19];
    const float* wpool= (const float*)d_in[20];
    const float* bpool= (const float*)d_in[21];
    const float* Wfc1 = (const float*)d_in[22];
    const float* bfc1 = (const float*)d_in[23];
    const float* Wfc2 = (const float*)d_in[24];
    const float* bfc2 = (const float*)d_in[25];
    const float* Wb   = (const float*)d_in[26];
    const float* bng  = (const float*)d_in[27];
    const float* bnb  = (const float*)d_in[28];
    const float* bnm  = (const float*)d_in[29];
    const float* bnv  = (const float*)d_in[30];
    float* out = (float*)d_out;
    float* ws = (float*)d_ws;

    size_t off = 0;
    float* beff  = ws + off; off += CCH;
    float* f3    = ws + off; off += BATCH*2*PP;
    float* f4    = ws + off; off += BATCH*2*PP;
    float* Af    = ws + off; off += BATCH*10*PP;
    float* Uf    = ws + off; off += BATCH*10*PP;
    float* f22   = ws + off; off += BATCH*PP;
    float* ccs   = ws + off; off += BATCH*PP;
    float* xw    = ws + off; off += BATCH*PP;
    float* T1    = ws + off; off += 324*324;
    float* T2    = ws + off; off += 324*81;
    off = (off + 3) & ~(size_t)3;   // 16B-align bf16 region
    __hip_bfloat16* Wh1p = (__hip_bfloat16*)(ws + off); off += (size_t)48*24*512/2;
    __hip_bfloat16* WAp  = (__hip_bfloat16*)(ws + off); off += (size_t)48*24*512/2;
    __hip_bfloat16* WBp  = (__hip_bfloat16*)(ws + off); off += (size_t)48*2*512/2;
    __hip_bfloat16* yT2  = (__hip_bfloat16*)(ws + off); off += (size_t)BATCH*2*CHW/2;
    __hip_bfloat16* f1b  = (__hip_bfloat16*)(ws + off); off += (size_t)BATCH*CCH*PP/2;
    __hip_bfloat16* f2b  = (__hip_bfloat16*)(ws + off); off += (size_t)BATCH*CCH*PP/2;
    off = (off + 3) & ~(size_t)3;
    __hip_bfloat16* inb2 = (__hip_bfloat16*)(ws + off); off += (size_t)BATCH*24*CHW/2;
    __hip_bfloat16* Wp   = (__hip_bfloat16*)(ws + off); off += (size_t)9*48*24*512/2;
    // xT2 aliases inb2: fuse12 consumes xT2 before k_finalize overwrites it
    __hip_bfloat16* xT2 = inb2;

    k_prep<<<dim3(CCH + 288 + 411), dim3(256), 0, stream>>>(
        W11, Wh2, Wl1, bh2, bl1, b11, Wh1, Wb, Wfc1, Wfc2,
        WAp, WBp, Wh1p, beff, Wp, T1, T2);
    k_xprep_f34<<<dim3(BATCH), dim3(256), 0, stream>>>(x, y, wh3, bh3, wl2, bl2, W12, b12, Wl3, bl3, xT2, yT2, f3, f4, Af);
    k_ssim_b2<<<dim3(26), dim3(256), 0, stream>>>(Af, Uf);
    k_fc<<<dim3(BATCH), dim3(128), 0, stream>>>(Uf, f3, f4, wcc, bcc, wpool, bpool, T1, bfc1, T2, bfc2, f22, ccs, xw);
    k_fuse12_mfma<<<dim3(8, BATCH), dim3(256), 0, stream>>>(xT2, yT2, Wh1p, WAp, WBp, bh1, beff, f1b, f2b);
    k_finalize<<<dim3(BATCH), dim3(256), 0, stream>>>(f1b, f2b, f22, ccs, xw, inb2);
    k_bconv_mfma<<<dim3(8, BATCH/2), dim3(256), 0, stream>>>(inb2, Wp, bng, bnb, bnm, bnv, out);
}

// Round 16
// 689.455 us; speedup vs baseline: 1.3188x; 1.0592x over previous
//
#include <hip/hip_runtime.h>
#include <hip/hip_bf16.h>
#include <math.h>

#define BATCH 256
#define CCH 768
#define LCH 64
#define PP 81
#define CHW 3072   // elems per chunk image: 96 rows x 32 ch

typedef __attribute__((ext_vector_type(8))) short short8v;
typedef __attribute__((ext_vector_type(4))) float f32x4;

#define GLL16(gp, lp) __builtin_amdgcn_global_load_lds( \
    (const __attribute__((address_space(1))) void*)(gp), \
    (__attribute__((address_space(3))) void*)(lp), 16, 0, 0)

// ---------------- P: merged weight prep (compose + wprep + fcprep) ----------
__global__ __launch_bounds__(256) void k_prep(
    const float* __restrict__ W11, const float* __restrict__ Wh2,
    const float* __restrict__ Wl1, const float* __restrict__ bh2,
    const float* __restrict__ bl1, const float* __restrict__ b11,
    const float* __restrict__ Wh1, const float* __restrict__ Wb,
    const float* __restrict__ Wfc1, const float* __restrict__ Wfc2,
    __hip_bfloat16* __restrict__ WAp, __hip_bfloat16* __restrict__ WBp,
    __hip_bfloat16* __restrict__ Wh1p, float* __restrict__ beff,
    __hip_bfloat16* __restrict__ Wp,
    float* __restrict__ T1, float* __restrict__ T2)
{
    int blk = blockIdx.x;
    int t = threadIdx.x;
    if (blk < CCH) {
        int o = blk;
        int ot = o >> 4, l15o = o & 15;
        const float* w11row = W11 + (size_t)o * CCH;
        for (int c = t; c < CCH; c += 256) {
            float s = 0.f;
            for (int k = 0; k < 512; ++k) s = fmaf(w11row[k], Wh2[(size_t)k*CCH + c], s);
            int ch = c >> 5, kg = (c >> 3) & 3, j = c & 7;
            size_t idx = (((size_t)ot*24 + ch) << 9) + (size_t)(kg*16 + l15o)*8 + j;
            WAp[idx]  = __float2bfloat16(s);
            Wh1p[idx] = __float2bfloat16(Wh1[(size_t)o*CCH + c]);
        }
        if (t < LCH) {
            float s = 0.f;
            for (int k = 0; k < 256; ++k) s = fmaf(w11row[512+k], Wl1[k*LCH + t], s);
            int ch = t >> 5, kg = (t >> 3) & 3, j = t & 7;
            size_t idx = (((size_t)ot*2 + ch) << 9) + (size_t)(kg*16 + l15o)*8 + j;
            WBp[idx] = __float2bfloat16(s);
        }
        if (t == 0) {
            float s = b11[o];
            for (int k = 0; k < 512; ++k) s = fmaf(w11row[k], bh2[k], s);
            for (int k = 0; k < 256; ++k) s = fmaf(w11row[512+k], bl1[k], s);
            beff[o] = s;
        }
    } else if (blk < CCH + 288) {
        int id = blk - CCH;
        int ot = id / 6;
        int i  = (id - ot*6)*256 + t;
        int oi = i / 96, c8 = i - oi*96;
        const float* src = Wb + ((size_t)(ot*16 + oi)*CCH + c8*8)*9;
        int ch = c8 >> 2;
        int lane8 = (((c8 & 3)*16) + oi)*8;
        #pragma unroll
        for (int tt = 0; tt < 9; ++tt) {
            short8v v;
            #pragma unroll
            for (int j = 0; j < 8; ++j) {
                __hip_bfloat16 h = __float2bfloat16(src[j*9 + tt]);
                v[j] = __builtin_bit_cast(short, h);
            }
            *(short8v*)(Wp + ((((size_t)(tt*48 + ot))*24 + ch) << 9) + lane8) = v;
        }
    } else {
        int n = (blk - CCH - 288)*256 + t;
        if (n < 324*324) { int i = n / 324, j = n - i*324; T1[(size_t)j*324 + i] = Wfc1[n]; }
        if (n < 81*324)  { int q = n / 324, j = n - q*324; T2[(size_t)j*81 + q]  = Wfc2[n]; }
    }
}

// ---------------- XP: x,y -> swizzled chunk images; fuse34 + ssim_wh fused --
__global__ __launch_bounds__(256) void k_xprep_f34(
    const float* __restrict__ x, const float* __restrict__ y,
    const float* __restrict__ wh3, const float* __restrict__ bh3,
    const float* __restrict__ wl2, const float* __restrict__ bl2,
    const float* __restrict__ W12, const float* __restrict__ b12,
    const float* __restrict__ Wl3, const float* __restrict__ bl3,
    __hip_bfloat16* __restrict__ xT2, __hip_bfloat16* __restrict__ yT2,
    float* __restrict__ f3, float* __restrict__ f4, float* __restrict__ Af)
{
    int b = blockIdx.x;
    int tid = threadIdx.x;
    __shared__ float ls[64][82];
    __shared__ float red[243][4];
    __shared__ float zz[10][81];
    __shared__ float tb[10][81];
    int q = tid / 81, p81 = tid - q*81;
    bool act = tid < 243;
    // zero row 81 of every chunk (pad rows 82..95 never read)
    for (int i = tid; i < 24*32; i += 256) {
        int ch = i >> 5, c = i & 31;
        xT2[(((size_t)b*24 + ch)*96 + 81)*32 + c] = __float2bfloat16(0.f);
    }
    if (tid < 2*32) {
        int ch = tid >> 5, c = tid & 31;
        yT2[(((size_t)b*2 + ch)*96 + 81)*32 + c] = __float2bfloat16(0.f);
    }
    float sx = 0.f;
    for (int c0 = 0; c0 < CCH; c0 += 64) {
        int ch0 = c0 >> 5;
        __syncthreads();
        for (int i = tid; i < 64*81; i += 256) {
            int c = i / 81, p = i - c*81;
            ls[c][p] = x[((size_t)b*CCH + c0 + c)*PP + p];
        }
        __syncthreads();
        for (int i = tid; i < 81*64; i += 256) {
            int p = i >> 6, c = i & 63;
            int ch = ch0 + (c >> 5), cc = c & 31;
            int s = cc >> 3, j = cc & 7;
            int slot = s ^ ((p >> 1) & 3);
            xT2[(((size_t)b*24 + ch)*96 + p)*32 + slot*8 + j] = __float2bfloat16(ls[c][p]);
        }
        if (act)
            for (int c = q; c < 64; c += 3)
                sx = fmaf(wh3[c0+c], ls[c][p81], sx);
    }
    __syncthreads();
    for (int i = tid; i < 64*81; i += 256) {
        int c = i / 81, p = i - c*81;
        ls[c][p] = y[((size_t)b*LCH + c)*PP + p];
    }
    __syncthreads();
    for (int i = tid; i < 81*64; i += 256) {
        int p = i >> 6, c = i & 63;
        int ch = c >> 5, cc = c & 31;
        int s = cc >> 3, j = cc & 7;
        int slot = s ^ ((p >> 1) & 3);
        yT2[(((size_t)b*2 + ch)*96 + p)*32 + slot*8 + j] = __float2bfloat16(ls[c][p]);
    }
    float sy = 0.f, s40 = 0.f, s41 = 0.f;
    if (act) {
        for (int c = q; c < 64; c += 3) {
            float v = ls[c][p81];
            sy  = fmaf(wl2[c], v, sy);
            s40 = fmaf(Wl3[c], v, s40);
            s41 = fmaf(Wl3[LCH+c], v, s41);
        }
        red[tid][0]=sx; red[tid][1]=sy; red[tid][2]=s40; red[tid][3]=s41;
    }
    __syncthreads();
    if (tid < 81) {
        float SX  = red[tid][0]+red[tid+81][0]+red[tid+162][0];
        float SY  = red[tid][1]+red[tid+81][1]+red[tid+162][1];
        float S40 = red[tid][2]+red[tid+81][2]+red[tid+162][2];
        float S41 = red[tid][3]+red[tid+81][3]+red[tid+162][3];
        float t3a = SX + bh3[0];
        float t3b = SY + bl2[0];
        float f30 = W12[0]*t3a + W12[1]*t3b + b12[0];
        float f31 = W12[2]*t3a + W12[3]*t3b + b12[1];
        float f40 = S40 + bl3[0];
        float f41 = S41 + bl3[1];
        f3[(b*2+0)*PP+tid] = f30; f3[(b*2+1)*PP+tid] = f31;
        f4[(b*2+0)*PP+tid] = f40; f4[(b*2+1)*PP+tid] = f41;
        zz[0][tid]=f30; zz[1][tid]=f40; zz[2][tid]=f30*f30; zz[3][tid]=f40*f40; zz[4][tid]=f30*f40;
        zz[5][tid]=f31; zz[6][tid]=f41; zz[7][tid]=f31*f31; zz[8][tid]=f41*f41; zz[9][tid]=f31*f41;
    }
    __syncthreads();
    for (int i = tid; i < 10*81; i += 256) {
        int f = i / 81, p = i - f*81;
        int yy = p/9, xx = p - yy*9;
        float s = 0.f;
        #pragma unroll
        for (int d = -3; d <= 3; ++d) {
            int j = xx + d;
            j = (j < 0) ? (-1-j) : ((j > 8) ? (17-j) : j);
            s += zz[f][yy*9+j];
        }
        tb[f][p] = s * (1.f/7.f);
    }
    __syncthreads();
    for (int i = tid; i < 10*81; i += 256) {
        int f = i / 81, p = i - f*81;
        int yy = p/9, xx = p - yy*9;
        float s = 0.f;
        #pragma unroll
        for (int d = -3; d <= 3; ++d) {
            int j = yy + d;
            j = (j < 0) ? (-1-j) : ((j > 8) ? (17-j) : j);
            s += tb[f][j*9+xx];
        }
        Af[((size_t)b*10 + f)*81 + p] = s * (1.f/7.f);
    }
}

// ---------------- S3: box-7 along batch, LDS-tiled --------------------------
__global__ __launch_bounds__(256) void k_ssim_b2(
    const float* __restrict__ A, float* __restrict__ U)
{
    int col0 = blockIdx.x * 32;
    int tid = threadIdx.x;
    __shared__ float lsb[256][33];
    for (int i = tid; i < 256*32; i += 256) {
        int j = i >> 5, cc = i & 31;
        int col = col0 + cc;
        lsb[j][cc] = (col < 810) ? A[(size_t)j*810 + col] : 0.f;
    }
    __syncthreads();
    for (int i = tid; i < 256*32; i += 256) {
        int b = i >> 5, cc = i & 31;
        float s = 0.f;
        #pragma unroll
        for (int d = -3; d <= 3; ++d) {
            int j = b + d;
            j = (j < 0) ? (-1-j) : ((j > 255) ? (511-j) : j);
            s += lsb[j][cc];
        }
        int col = col0 + cc;
        if (col < 810) U[(size_t)b*810 + col] = s * (1.f/7.f);
    }
}

// ---------------- F: ssim_comb + pool + fc1(gelu) + fc2(leaky) --------------
__global__ __launch_bounds__(128) void k_fc(
    const float* __restrict__ U, const float* __restrict__ f3,
    const float* __restrict__ f4, const float* __restrict__ wcc,
    const float* __restrict__ bcc,
    const float* __restrict__ wpool, const float* __restrict__ bpool,
    const float* __restrict__ T1, const float* __restrict__ bfc1,
    const float* __restrict__ T2, const float* __restrict__ bfc2,
    float* __restrict__ f22, float* __restrict__ ccs,
    float* __restrict__ xw)
{
    int b = blockIdx.x;
    int tid = threadIdx.x;
    __shared__ float xc[324];
    __shared__ float h1[324];
    __shared__ float pr[2][81], ps[2][81];
    const float cov = 343.f/342.f, C1c = 1e-4f, C2c = 9e-4f;
    for (int i = tid; i < 162; i += 128) {
        int k = i / 81, p = i - k*81;
        const float* u = U + (size_t)b*810 + (k*5)*81 + p;
        float ux = u[0], uy = u[81], uxx = u[162], uyy = u[243], uxy = u[324];
        float vx = cov*(uxx - ux*ux), vy = cov*(uyy - uy*uy), vxy = cov*(uxy - ux*uy);
        float S = ((2.f*ux*uy + C1c)*(2.f*vxy + C2c)) /
                  ((ux*ux + uy*uy + C1c)*(vx + vy + C2c));
        float a = f4[(b*2+k)*81+p] + S*f3[(b*2+k)*81+p];
        pr[k][p] = wcc[k]*a;
        ps[k][p] = wcc[k]*S;
    }
    __syncthreads();
    if (tid < 81) {
        float fv = pr[0][tid] + pr[1][tid] + bcc[0];
        float cv = ps[0][tid] + ps[1][tid] + bcc[0];
        f22[b*81+tid] = fv;
        ccs[b*81+tid] = cv;
        xc[tid] = fv; xc[243+tid] = fv;
    }
    __syncthreads();
    for (int i = tid; i < 162; i += 128) {
        int k = i / 81, p = i - k*81;
        int yy = p/9, xx = p - yy*9;
        float s = bpool[k];
        #pragma unroll
        for (int dy = -1; dy <= 1; ++dy)
            #pragma unroll
            for (int dx = -1; dx <= 1; ++dx) {
                int Y = yy+dy, X = xx+dx;
                if (Y >= 0 && Y < 9 && X >= 0 && X < 9)
                    s = fmaf(wpool[k*9 + (dy+1)*3 + (dx+1)], xc[Y*9+X], s);
            }
        xc[81+i] = s;
    }
    __syncthreads();
    for (int i = tid; i < 324; i += 128) {
        float s = bfc1[i];
        for (int j = 0; j < 324; ++j) s = fmaf(T1[(size_t)j*324 + i], xc[j], s);
        h1[i] = 0.5f*s*(1.f + erff(s*0.70710678118654752f));
    }
    __syncthreads();
    for (int qq = tid; qq < 81; qq += 128) {
        float s = bfc2[qq];
        for (int j = 0; j < 324; ++j) s = fmaf(T2[(size_t)j*81 + qq], h1[j], s);
        xw[b*81+qq] = (s > 0.f) ? s : 0.01f*s;
    }
}

// ---------------- K1 v10: fuse12 MFMA, direct-global B, no LDS, no barriers -
__global__ __launch_bounds__(256) void k_fuse12_mfma(
    const __hip_bfloat16* __restrict__ xT2,   // [B][24][96][32] swizzled image
    const __hip_bfloat16* __restrict__ yT2,   // [B][2][96][32]
    const __hip_bfloat16* __restrict__ Wh1p,
    const __hip_bfloat16* __restrict__ WAp,
    const __hip_bfloat16* __restrict__ WBp,
    const float* __restrict__ bh1, const float* __restrict__ beff,
    __hip_bfloat16* __restrict__ f1, __hip_bfloat16* __restrict__ f2)
{
    int oy = blockIdx.x;          // 0..7, o-extent 96; XCD = linear%8 = oy
    int b  = blockIdx.y;
    int tid = threadIdx.x;
    int w    = tid >> 6;          // 0..3
    int g    = w >> 1;            // 0 -> f1 (Wh1), 1 -> f2 (WA, WB)
    int nh   = w & 1;             // n-half
    int lane = tid & 63;
    int l15  = lane & 15;
    int kg   = lane >> 4;

    int spoff[3];
    #pragma unroll
    for (int nl = 0; nl < 3; ++nl) {
        int p = (nh*3 + nl)*16 + l15;
        int sp = (p < PP) ? p : 81;
        spoff[nl] = sp*32 + ((kg ^ ((sp >> 1) & 3)) << 3);
    }

    f32x4 acc[6][3];
    #pragma unroll
    for (int m = 0; m < 6; ++m)
        #pragma unroll
        for (int nl = 0; nl < 3; ++nl)
            acc[m][nl] = (f32x4){0.f,0.f,0.f,0.f};

    const __hip_bfloat16* xb = xT2 + (size_t)b*24*CHW;
    const __hip_bfloat16* yb = yT2 + (size_t)b*2*CHW;
    const __hip_bfloat16* Wsel = g ? WAp : Wh1p;
    int otb = oy*6;

    for (int ch = 0; ch < 24; ++ch) {
        const __hip_bfloat16* cb = xb + (size_t)ch*CHW;
        short8v bf[3];
        #pragma unroll
        for (int nl = 0; nl < 3; ++nl)
            bf[nl] = *(const short8v*)&cb[spoff[nl]];
        short8v a[6];
        #pragma unroll
        for (int m = 0; m < 6; ++m)
            a[m] = *(const short8v*)(Wsel + ((((size_t)(otb + m))*24 + ch) << 9) + (lane<<3));
        #pragma unroll
        for (int nl = 0; nl < 3; ++nl)
            #pragma unroll
            for (int m = 0; m < 6; ++m)
                acc[m][nl] = __builtin_amdgcn_mfma_f32_16x16x32_bf16(a[m], bf[nl], acc[m][nl], 0, 0, 0);
    }

    if (g == 1) {
        for (int ch2 = 0; ch2 < 2; ++ch2) {
            const __hip_bfloat16* cb = yb + (size_t)ch2*CHW;
            short8v bf[3];
            #pragma unroll
            for (int nl = 0; nl < 3; ++nl)
                bf[nl] = *(const short8v*)&cb[spoff[nl]];
            short8v a[6];
            #pragma unroll
            for (int m = 0; m < 6; ++m)
                a[m] = *(const short8v*)(WBp + ((((size_t)(otb + m))*2 + ch2) << 9) + (lane<<3));
            #pragma unroll
            for (int nl = 0; nl < 3; ++nl)
                #pragma unroll
                for (int m = 0; m < 6; ++m)
                    acc[m][nl] = __builtin_amdgcn_mfma_f32_16x16x32_bf16(a[m], bf[nl], acc[m][nl], 0, 0, 0);
        }
    }

    __hip_bfloat16* dst = g ? f2 : f1;
    const float* bias = g ? beff : bh1;
    #pragma unroll
    for (int m = 0; m < 6; ++m) {
        #pragma unroll
        for (int r = 0; r < 4; ++r) {
            int o = (otb + m)*16 + kg*4 + r;
            float bb = bias[o];
            #pragma unroll
            for (int nl = 0; nl < 3; ++nl) {
                int p = (nh*3 + nl)*16 + l15;
                if (p < PP)
                    dst[((size_t)b*CCH + o)*PP + p] = __float2bfloat16(acc[m][nl][r] + bb);
            }
        }
    }
}

// ---------------- FZ: cor sums + alpha/gamma + swizzled-image build ---------
__global__ __launch_bounds__(256) void k_finalize(
    const __hip_bfloat16* __restrict__ f1, const __hip_bfloat16* __restrict__ f2,
    const float* __restrict__ f22, const float* __restrict__ ccs,
    const float* __restrict__ xw,
    __hip_bfloat16* __restrict__ inb2)
{
    int b = blockIdx.x;
    int tid = threadIdx.x;
    __shared__ float red[243][5];
    __shared__ float sal[81], sga[81], scm[81];
    __shared__ float ls[64][82];
    // zero row 81 of every chunk
    for (int i = tid; i < 24*32; i += 256) {
        int ch = i >> 5, c = i & 31;
        inb2[(((size_t)b*24 + ch)*96 + 81)*32 + c] = __float2bfloat16(0.f);
    }
    bool act = tid < 243;
    float Sxx=0.f, Syy=0.f, Sxy=0.f, Sx=0.f, Sy=0.f;
    const __hip_bfloat16* A = f1 + (size_t)b*CCH*PP;
    const __hip_bfloat16* C = f2 + (size_t)b*CCH*PP;
    if (act) {
        for (int c0 = 0; c0 < CCH; c0 += 3) {
            float u = __bfloat162float(A[(size_t)c0*PP + tid]);
            float v = __bfloat162float(C[(size_t)c0*PP + tid]);
            Sxx = fmaf(u,u,Sxx); Syy = fmaf(v,v,Syy); Sxy = fmaf(u,v,Sxy);
            Sx += u; Sy += v;
        }
        red[tid][0]=Sxx; red[tid][1]=Syy; red[tid][2]=Sxy; red[tid][3]=Sx; red[tid][4]=Sy;
    }
    __syncthreads();
    if (tid < 81) {
        float xx = red[tid][0]+red[tid+81][0]+red[tid+162][0];
        float yy = red[tid][1]+red[tid+81][1]+red[tid+162][1];
        float xy = red[tid][2]+red[tid+81][2]+red[tid+162][2];
        float sx = red[tid][3]+red[tid+81][3]+red[tid+162][3];
        float sy = red[tid][4]+red[tid+81][4]+red[tid+162][4];
        float cor1 = xy / fmaxf(sqrtf(xx)*sqrtf(yy), 1e-8f);
        float al = 0.5f*(1.f - cor1);
        float sum21 = sx + al*sy;
        float n21 = sqrtf(fmaxf(xx + 2.f*al*xy + al*al*yy, 0.f));
        int t = b*81 + tid;
        float fv = f22[t];
        float cor2 = (fv * sum21) / fmaxf(n21 * 27.712812921102035f * fabsf(fv), 1e-8f);
        float be = 0.5f*(1.f - cor2 + ccs[t]);
        sal[tid] = al;
        sga[tid] = be * fv;
        scm[tid] = 1.f + xw[t];
    }
    for (int c0 = 0; c0 < CCH; c0 += 64) {
        int ch0 = c0 >> 5;
        __syncthreads();
        for (int i = tid; i < 64*81; i += 256) {
            int c = i / 81, p = i - c*81;
            size_t gidx = ((size_t)b*CCH + c0 + c)*PP + p;
            float u = __bfloat162float(f1[gidx]);
            float v = __bfloat162float(f2[gidx]);
            ls[c][p] = scm[p]*(u + sal[p]*v + sga[p]);
        }
        __syncthreads();
        for (int i = tid; i < 81*64; i += 256) {
            int p = i >> 6, c = i & 63;
            int ch = ch0 + (c >> 5), cc = c & 31;
            int s = cc >> 3, j = cc & 7;
            int slot = s ^ ((p >> 1) & 3);
            inb2[(((size_t)b*24 + ch)*96 + p)*32 + slot*8 + j] = __float2bfloat16(ls[c][p]);
        }
    }
}

// ---------------- KB (R12-exact): bconv MFMA, 2 batches/block, 3-chunk groups
__global__ __launch_bounds__(256, 2) void k_bconv_mfma(
    const __hip_bfloat16* __restrict__ inb2,  // [B][24][96][32] swizzled image
    const __hip_bfloat16* __restrict__ Wp,    // packed [9][48][24][512]
    const float* __restrict__ bn_g, const float* __restrict__ bn_b,
    const float* __restrict__ bn_m, const float* __restrict__ bn_v,
    float* __restrict__ out)
{
    int oy = blockIdx.x;        // 0..7, o-extent 96; XCD = linear%8 = oy
    int b0 = blockIdx.y * 2;
    int tid = threadIdx.x;
    int w    = tid >> 6;        // 0..3
    int bi   = w >> 1;          // batch within pair
    int nh   = w & 1;           // n-half -> n-tiles {3*nh..3*nh+2}
    int lane = tid & 63;
    int l15  = lane & 15;
    int kg   = lane >> 4;

    __shared__ __align__(16) __hip_bfloat16 ls[6*CHW];   // [2 b][3 chunks][3072] = 36 KB

    int spoff[9][3];
    #pragma unroll
    for (int t = 0; t < 9; ++t) {
        int dy = t/3 - 1, dx = t%3 - 1;
        #pragma unroll
        for (int nl = 0; nl < 3; ++nl) {
            int p = (nh*3 + nl)*16 + l15;
            int yy = p/9, xx = p - yy*9;
            int Y = yy + dy, X = xx + dx;
            bool ok = (p < PP) && (Y >= 0) && (Y < 9) && (X >= 0) && (X < 9);
            int sp = ok ? (Y*9 + X) : 81;
            spoff[t][nl] = sp*32 + ((kg ^ ((sp >> 1) & 3)) << 3);
        }
    }

    f32x4 acc[6][3];
    #pragma unroll
    for (int m = 0; m < 6; ++m)
        #pragma unroll
        for (int nl = 0; nl < 3; ++nl)
            acc[m][nl] = (f32x4){0.f,0.f,0.f,0.f};

    const __hip_bfloat16* img0 = inb2 + (size_t)(b0    )*24*CHW;
    const __hip_bfloat16* img1 = inb2 + (size_t)(b0 + 1)*24*CHW;
    int otb = oy*6;

    for (int grp = 0; grp < 8; ++grp) {
        __syncthreads();
        // stage 3 chunks x 2 batches = 36 slabs of 1KB; 9 per wave
        #pragma unroll
        for (int k = 0; k < 9; ++k) {
            int it = w + 4*k;                 // 0..35
            int bb = it / 18;
            int r  = it - bb*18;
            int cc = r / 6, sub = r - cc*6;
            const __hip_bfloat16* src =
                (bb ? img1 : img0) + (size_t)(grp*3 + cc)*CHW + sub*512;
            GLL16(src + lane*8, &ls[(size_t)(bb*3 + cc)*CHW + sub*512]);
        }
        __syncthreads();
        for (int cc = 0; cc < 3; ++cc) {
            int ch = grp*3 + cc;
            const __hip_bfloat16* lb = &ls[(size_t)(bi*3 + cc)*CHW];
            #pragma unroll
            for (int t = 0; t < 9; ++t) {
                short8v a[6];
                #pragma unroll
                for (int m = 0; m < 6; ++m)
                    a[m] = *(const short8v*)(Wp + (((size_t)(t*48 + otb + m)*24 + ch) << 9) + (lane<<3));
                #pragma unroll
                for (int nl = 0; nl < 3; ++nl) {
                    short8v bf = *(const short8v*)&lb[spoff[t][nl]];
                    #pragma unroll
                    for (int m = 0; m < 6; ++m)
                        acc[m][nl] = __builtin_amdgcn_mfma_f32_16x16x32_bf16(a[m], bf, acc[m][nl], 0, 0, 0);
                }
            }
        }
    }

    int b = b0 + bi;
    #pragma unroll
    for (int m = 0; m < 6; ++m) {
        #pragma unroll
        for (int r = 0; r < 4; ++r) {
            int o = (otb + m)*16 + kg*4 + r;
            float sc = bn_g[o] * rsqrtf(bn_v[o] + 1e-5f);
            float mn = bn_m[o], bt = bn_b[o];
            #pragma unroll
            for (int nl = 0; nl < 3; ++nl) {
                int p = (nh*3 + nl)*16 + l15;
                if (p < PP) {
                    float v = (acc[m][nl][r] - mn) * sc + bt;
                    out[((size_t)b*CCH + o)*PP + p] = (v > 0.f) ? v : 0.01f*v;
                }
            }
        }
    }
}

extern "C" void kernel_launch(void* const* d_in, const int* in_sizes, int n_in,
                              void* d_out, int out_size, void* d_ws, size_t ws_size,
                              hipStream_t stream)
{
    (void)in_sizes; (void)n_in; (void)out_size; (void)ws_size;
    const float* x    = (const float*)d_in[0];
    const float* y    = (const float*)d_in[1];
    const float* Wh1  = (const float*)d_in[2];
    const float* bh1  = (const float*)d_in[3];
    const float* W11  = (const float*)d_in[4];
    const float* b11  = (const float*)d_in[5];
    const float* Wh2  = (const float*)d_in[6];
    const float* bh2  = (const float*)d_in[7];
    const float* Wl1  = (const float*)d_in[8];
    const float* bl1  = (const float*)d_in[9];
    const float* wh3  = (const float*)d_in[10];
    const float* bh3  = (const float*)d_in[11];
    const float* wl2  = (const float*)d_in[12];
    const float* bl2  = (const float*)d_in[13];
    const float* W12  = (const float*)d_in[14];
    const float* b12  = (const float*)d_in[15];
    const float* Wl3  = (const float*)d_in[16];
    const float* bl3  = (const float*)d_in[17];
    const float* wcc  = (const float*)d_in[18];
    const float* bcc  = (const float*)d_in[19];
    const float* wpool= (const float*)d_in[20];
    const float* bpool= (const float*)d_in[21];
    const float* Wfc1 = (const float*)d_in[22];
    const float* bfc1 = (const float*)d_in[23];
    const float* Wfc2 = (const float*)d_in[24];
    const float* bfc2 = (const float*)d_in[25];
    const float* Wb   = (const float*)d_in[26];
    const float* bng  = (const float*)d_in[27];
    const float* bnb  = (const float*)d_in[28];
    const float* bnm  = (const float*)d_in[29];
    const float* bnv  = (const float*)d_in[30];
    float* out = (float*)d_out;
    float* ws = (float*)d_ws;

    size_t off = 0;
    float* beff  = ws + off; off += CCH;
    float* f3    = ws + off; off += BATCH*2*PP;
    float* f4    = ws + off; off += BATCH*2*PP;
    float* Af    = ws + off; off += BATCH*10*PP;
    float* Uf    = ws + off; off += BATCH*10*PP;
    float* f22   = ws + off; off += BATCH*PP;
    float* ccs   = ws + off; off += BATCH*PP;
    float* xw    = ws + off; off += BATCH*PP;
    float* T1    = ws + off; off += 324*324;
    float* T2    = ws + off; off += 324*81;
    off = (off + 3) & ~(size_t)3;   // 16B-align bf16 region
    __hip_bfloat16* Wh1p = (__hip_bfloat16*)(ws + off); off += (size_t)48*24*512/2;
    __hip_bfloat16* WAp  = (__hip_bfloat16*)(ws + off); off += (size_t)48*24*512/2;
    __hip_bfloat16* WBp  = (__hip_bfloat16*)(ws + off); off += (size_t)48*2*512/2;
    __hip_bfloat16* yT2  = (__hip_bfloat16*)(ws + off); off += (size_t)BATCH*2*CHW/2;
    __hip_bfloat16* f1b  = (__hip_bfloat16*)(ws + off); off += (size_t)BATCH*CCH*PP/2;
    __hip_bfloat16* f2b  = (__hip_bfloat16*)(ws + off); off += (size_t)BATCH*CCH*PP/2;
    off = (off + 3) & ~(size_t)3;
    __hip_bfloat16* inb2 = (__hip_bfloat16*)(ws + off); off += (size_t)BATCH*24*CHW/2;
    __hip_bfloat16* Wp   = (__hip_bfloat16*)(ws + off); off += (size_t)9*48*24*512/2;
    // xT2 aliases inb2: fuse12 consumes xT2 before k_finalize overwrites it
    __hip_bfloat16* xT2 = inb2;

    k_prep<<<dim3(CCH + 288 + 411), dim3(256), 0, stream>>>(
        W11, Wh2, Wl1, bh2, bl1, b11, Wh1, Wb, Wfc1, Wfc2,
        WAp, WBp, Wh1p, beff, Wp, T1, T2);
    k_xprep_f34<<<dim3(BATCH), dim3(256), 0, stream>>>(x, y, wh3, bh3, wl2, bl2, W12, b12, Wl3, bl3, xT2, yT2, f3, f4, Af);
    k_ssim_b2<<<dim3(26), dim3(256), 0, stream>>>(Af, Uf);
    k_fc<<<dim3(BATCH), dim3(128), 0, stream>>>(Uf, f3, f4, wcc, bcc, wpool, bpool, T1, bfc1, T2, bfc2, f22, ccs, xw);
    k_fuse12_mfma<<<dim3(8, BATCH), dim3(256), 0, stream>>>(xT2, yT2, Wh1p, WAp, WBp, bh1, beff, f1b, f2b);
    k_finalize<<<dim3(BATCH), dim3(256), 0, stream>>>(f1b, f2b, f22, ccs, xw, inb2);
    k_bconv_mfma<<<dim3(8, BATCH/2), dim3(256), 0, stream>>>(inb2, Wp, bng, bnb, bnm, bnv, out);
}

// Round 17
// 684.266 us; speedup vs baseline: 1.3288x; 1.0076x over previous
//
#include <hip/hip_runtime.h>
#include <hip/hip_bf16.h>
#include <math.h>

#define BATCH 256
#define CCH 768
#define LCH 64
#define PP 81
#define CHW 3072   // elems per chunk image: 96 rows x 32 ch

typedef __attribute__((ext_vector_type(8))) short short8v;
typedef __attribute__((ext_vector_type(4))) float f32x4;

#define GLL16(gp, lp) __builtin_amdgcn_global_load_lds( \
    (const __attribute__((address_space(1))) void*)(gp), \
    (__attribute__((address_space(3))) void*)(lp), 16, 0, 0)

// ---------------- P: merged weight prep (compose + wprep + fcprep) ----------
__global__ __launch_bounds__(256) void k_prep(
    const float* __restrict__ W11, const float* __restrict__ Wh2,
    const float* __restrict__ Wl1, const float* __restrict__ bh2,
    const float* __restrict__ bl1, const float* __restrict__ b11,
    const float* __restrict__ Wh1, const float* __restrict__ Wb,
    const float* __restrict__ Wfc1, const float* __restrict__ Wfc2,
    __hip_bfloat16* __restrict__ WAp, __hip_bfloat16* __restrict__ WBp,
    __hip_bfloat16* __restrict__ Wh1p, float* __restrict__ beff,
    __hip_bfloat16* __restrict__ Wp,
    float* __restrict__ T1, float* __restrict__ T2)
{
    int blk = blockIdx.x;
    int t = threadIdx.x;
    if (blk < CCH) {
        int o = blk;
        int ot = o >> 4, l15o = o & 15;
        const float* w11row = W11 + (size_t)o * CCH;
        for (int c = t; c < CCH; c += 256) {
            float s = 0.f;
            for (int k = 0; k < 512; ++k) s = fmaf(w11row[k], Wh2[(size_t)k*CCH + c], s);
            int ch = c >> 5, kg = (c >> 3) & 3, j = c & 7;
            size_t idx = (((size_t)ot*24 + ch) << 9) + (size_t)(kg*16 + l15o)*8 + j;
            WAp[idx]  = __float2bfloat16(s);
            Wh1p[idx] = __float2bfloat16(Wh1[(size_t)o*CCH + c]);
        }
        if (t < LCH) {
            float s = 0.f;
            for (int k = 0; k < 256; ++k) s = fmaf(w11row[512+k], Wl1[k*LCH + t], s);
            int ch = t >> 5, kg = (t >> 3) & 3, j = t & 7;
            size_t idx = (((size_t)ot*2 + ch) << 9) + (size_t)(kg*16 + l15o)*8 + j;
            WBp[idx] = __float2bfloat16(s);
        }
        if (t == 0) {
            float s = b11[o];
            for (int k = 0; k < 512; ++k) s = fmaf(w11row[k], bh2[k], s);
            for (int k = 0; k < 256; ++k) s = fmaf(w11row[512+k], bl1[k], s);
            beff[o] = s;
        }
    } else if (blk < CCH + 288) {
        int id = blk - CCH;
        int ot = id / 6;
        int i  = (id - ot*6)*256 + t;
        int oi = i / 96, c8 = i - oi*96;
        const float* src = Wb + ((size_t)(ot*16 + oi)*CCH + c8*8)*9;
        int ch = c8 >> 2;
        int lane8 = (((c8 & 3)*16) + oi)*8;
        #pragma unroll
        for (int tt = 0; tt < 9; ++tt) {
            short8v v;
            #pragma unroll
            for (int j = 0; j < 8; ++j) {
                __hip_bfloat16 h = __float2bfloat16(src[j*9 + tt]);
                v[j] = __builtin_bit_cast(short, h);
            }
            *(short8v*)(Wp + ((((size_t)(tt*48 + ot))*24 + ch) << 9) + lane8) = v;
        }
    } else {
        int n = (blk - CCH - 288)*256 + t;
        if (n < 324*324) { int i = n / 324, j = n - i*324; T1[(size_t)j*324 + i] = Wfc1[n]; }
        if (n < 81*324)  { int q = n / 324, j = n - q*324; T2[(size_t)j*81 + q]  = Wfc2[n]; }
    }
}

// ---------------- XP: 512 thr; x,y -> swizzled images; fuse34 + ssim_wh -----
__global__ __launch_bounds__(512) void k_xprep_f34(
    const float* __restrict__ x, const float* __restrict__ y,
    const float* __restrict__ wh3, const float* __restrict__ bh3,
    const float* __restrict__ wl2, const float* __restrict__ bl2,
    const float* __restrict__ W12, const float* __restrict__ b12,
    const float* __restrict__ Wl3, const float* __restrict__ bl3,
    __hip_bfloat16* __restrict__ xT2, __hip_bfloat16* __restrict__ yT2,
    float* __restrict__ f3, float* __restrict__ f4, float* __restrict__ Af)
{
    int b = blockIdx.x;
    int tid = threadIdx.x;
    __shared__ float ls[64][82];
    __shared__ float red[486][4];
    __shared__ float zz[10][81];
    __shared__ float tb[10][81];
    int q = tid / 81, p81 = tid - q*81;
    bool act = tid < 486;
    // zero row 81 of every chunk (pad rows 82..95 never read)
    for (int i = tid; i < 24*32; i += 512) {
        int ch = i >> 5, c = i & 31;
        xT2[(((size_t)b*24 + ch)*96 + 81)*32 + c] = __float2bfloat16(0.f);
    }
    if (tid < 2*32) {
        int ch = tid >> 5, c = tid & 31;
        yT2[(((size_t)b*2 + ch)*96 + 81)*32 + c] = __float2bfloat16(0.f);
    }
    float sx = 0.f;
    for (int c0 = 0; c0 < CCH; c0 += 64) {
        int ch0 = c0 >> 5;
        __syncthreads();
        for (int i = tid; i < 64*81; i += 512) {
            int c = i / 81, p = i - c*81;
            ls[c][p] = x[((size_t)b*CCH + c0 + c)*PP + p];
        }
        __syncthreads();
        for (int i = tid; i < 81*64; i += 512) {
            int p = i >> 6, c = i & 63;
            int ch = ch0 + (c >> 5), cc = c & 31;
            int s = cc >> 3, j = cc & 7;
            int slot = s ^ ((p >> 1) & 3);
            xT2[(((size_t)b*24 + ch)*96 + p)*32 + slot*8 + j] = __float2bfloat16(ls[c][p]);
        }
        if (act)
            for (int c = q; c < 64; c += 6)
                sx = fmaf(wh3[c0+c], ls[c][p81], sx);
    }
    __syncthreads();
    for (int i = tid; i < 64*81; i += 512) {
        int c = i / 81, p = i - c*81;
        ls[c][p] = y[((size_t)b*LCH + c)*PP + p];
    }
    __syncthreads();
    for (int i = tid; i < 81*64; i += 512) {
        int p = i >> 6, c = i & 63;
        int ch = c >> 5, cc = c & 31;
        int s = cc >> 3, j = cc & 7;
        int slot = s ^ ((p >> 1) & 3);
        yT2[(((size_t)b*2 + ch)*96 + p)*32 + slot*8 + j] = __float2bfloat16(ls[c][p]);
    }
    float sy = 0.f, s40 = 0.f, s41 = 0.f;
    if (act) {
        for (int c = q; c < 64; c += 6) {
            float v = ls[c][p81];
            sy  = fmaf(wl2[c], v, sy);
            s40 = fmaf(Wl3[c], v, s40);
            s41 = fmaf(Wl3[LCH+c], v, s41);
        }
        red[tid][0]=sx; red[tid][1]=sy; red[tid][2]=s40; red[tid][3]=s41;
    }
    __syncthreads();
    if (tid < 81) {
        float SX = 0.f, SY = 0.f, S40 = 0.f, S41 = 0.f;
        #pragma unroll
        for (int k = 0; k < 6; ++k) {
            SX  += red[tid+81*k][0];
            SY  += red[tid+81*k][1];
            S40 += red[tid+81*k][2];
            S41 += red[tid+81*k][3];
        }
        float t3a = SX + bh3[0];
        float t3b = SY + bl2[0];
        float f30 = W12[0]*t3a + W12[1]*t3b + b12[0];
        float f31 = W12[2]*t3a + W12[3]*t3b + b12[1];
        float f40 = S40 + bl3[0];
        float f41 = S41 + bl3[1];
        f3[(b*2+0)*PP+tid] = f30; f3[(b*2+1)*PP+tid] = f31;
        f4[(b*2+0)*PP+tid] = f40; f4[(b*2+1)*PP+tid] = f41;
        zz[0][tid]=f30; zz[1][tid]=f40; zz[2][tid]=f30*f30; zz[3][tid]=f40*f40; zz[4][tid]=f30*f40;
        zz[5][tid]=f31; zz[6][tid]=f41; zz[7][tid]=f31*f31; zz[8][tid]=f41*f41; zz[9][tid]=f31*f41;
    }
    __syncthreads();
    for (int i = tid; i < 10*81; i += 512) {
        int f = i / 81, p = i - f*81;
        int yy = p/9, xx = p - yy*9;
        float s = 0.f;
        #pragma unroll
        for (int d = -3; d <= 3; ++d) {
            int j = xx + d;
            j = (j < 0) ? (-1-j) : ((j > 8) ? (17-j) : j);
            s += zz[f][yy*9+j];
        }
        tb[f][p] = s * (1.f/7.f);
    }
    __syncthreads();
    for (int i = tid; i < 10*81; i += 512) {
        int f = i / 81, p = i - f*81;
        int yy = p/9, xx = p - yy*9;
        float s = 0.f;
        #pragma unroll
        for (int d = -3; d <= 3; ++d) {
            int j = yy + d;
            j = (j < 0) ? (-1-j) : ((j > 8) ? (17-j) : j);
            s += tb[f][j*9+xx];
        }
        Af[((size_t)b*10 + f)*81 + p] = s * (1.f/7.f);
    }
}

// ---------------- S3: box-7 along batch, 8 cols/block, grid 102 -------------
__global__ __launch_bounds__(256) void k_ssim_b2(
    const float* __restrict__ A, float* __restrict__ U)
{
    int col0 = blockIdx.x * 8;
    int tid = threadIdx.x;
    __shared__ float lsb[256][9];
    for (int i = tid; i < 256*8; i += 256) {
        int j = i >> 3, cc = i & 7;
        int col = col0 + cc;
        lsb[j][cc] = (col < 810) ? A[(size_t)j*810 + col] : 0.f;
    }
    __syncthreads();
    for (int i = tid; i < 256*8; i += 256) {
        int b = i >> 3, cc = i & 7;
        float s = 0.f;
        #pragma unroll
        for (int d = -3; d <= 3; ++d) {
            int j = b + d;
            j = (j < 0) ? (-1-j) : ((j > 255) ? (511-j) : j);
            s += lsb[j][cc];
        }
        int col = col0 + cc;
        if (col < 810) U[(size_t)b*810 + col] = s * (1.f/7.f);
    }
}

// ---------------- F: 256 thr; ssim_comb + pool + fc1(gelu) + fc2(leaky) -----
__global__ __launch_bounds__(256) void k_fc(
    const float* __restrict__ U, const float* __restrict__ f3,
    const float* __restrict__ f4, const float* __restrict__ wcc,
    const float* __restrict__ bcc,
    const float* __restrict__ wpool, const float* __restrict__ bpool,
    const float* __restrict__ T1, const float* __restrict__ bfc1,
    const float* __restrict__ T2, const float* __restrict__ bfc2,
    float* __restrict__ f22, float* __restrict__ ccs,
    float* __restrict__ xw)
{
    int b = blockIdx.x;
    int tid = threadIdx.x;
    __shared__ float xc[324];
    __shared__ float h1[324];
    __shared__ float pr[2][81], ps[2][81];
    const float cov = 343.f/342.f, C1c = 1e-4f, C2c = 9e-4f;
    for (int i = tid; i < 162; i += 256) {
        int k = i / 81, p = i - k*81;
        const float* u = U + (size_t)b*810 + (k*5)*81 + p;
        float ux = u[0], uy = u[81], uxx = u[162], uyy = u[243], uxy = u[324];
        float vx = cov*(uxx - ux*ux), vy = cov*(uyy - uy*uy), vxy = cov*(uxy - ux*uy);
        float S = ((2.f*ux*uy + C1c)*(2.f*vxy + C2c)) /
                  ((ux*ux + uy*uy + C1c)*(vx + vy + C2c));
        float a = f4[(b*2+k)*81+p] + S*f3[(b*2+k)*81+p];
        pr[k][p] = wcc[k]*a;
        ps[k][p] = wcc[k]*S;
    }
    __syncthreads();
    if (tid < 81) {
        float fv = pr[0][tid] + pr[1][tid] + bcc[0];
        float cv = ps[0][tid] + ps[1][tid] + bcc[0];
        f22[b*81+tid] = fv;
        ccs[b*81+tid] = cv;
        xc[tid] = fv; xc[243+tid] = fv;
    }
    __syncthreads();
    for (int i = tid; i < 162; i += 256) {
        int k = i / 81, p = i - k*81;
        int yy = p/9, xx = p - yy*9;
        float s = bpool[k];
        #pragma unroll
        for (int dy = -1; dy <= 1; ++dy)
            #pragma unroll
            for (int dx = -1; dx <= 1; ++dx) {
                int Y = yy+dy, X = xx+dx;
                if (Y >= 0 && Y < 9 && X >= 0 && X < 9)
                    s = fmaf(wpool[k*9 + (dy+1)*3 + (dx+1)], xc[Y*9+X], s);
            }
        xc[81+i] = s;
    }
    __syncthreads();
    for (int i = tid; i < 324; i += 256) {
        float s = bfc1[i];
        for (int j = 0; j < 324; ++j) s = fmaf(T1[(size_t)j*324 + i], xc[j], s);
        h1[i] = 0.5f*s*(1.f + erff(s*0.70710678118654752f));
    }
    __syncthreads();
    for (int qq = tid; qq < 81; qq += 256) {
        float s = bfc2[qq];
        for (int j = 0; j < 324; ++j) s = fmaf(T2[(size_t)j*81 + qq], h1[j], s);
        xw[b*81+qq] = (s > 0.f) ? s : 0.01f*s;
    }
}

// ---------------- K1 v10: fuse12 MFMA, direct-global B, no LDS, no barriers -
__global__ __launch_bounds__(256) void k_fuse12_mfma(
    const __hip_bfloat16* __restrict__ xT2,   // [B][24][96][32] swizzled image
    const __hip_bfloat16* __restrict__ yT2,   // [B][2][96][32]
    const __hip_bfloat16* __restrict__ Wh1p,
    const __hip_bfloat16* __restrict__ WAp,
    const __hip_bfloat16* __restrict__ WBp,
    const float* __restrict__ bh1, const float* __restrict__ beff,
    __hip_bfloat16* __restrict__ f1, __hip_bfloat16* __restrict__ f2)
{
    int oy = blockIdx.x;          // 0..7, o-extent 96; XCD = linear%8 = oy
    int b  = blockIdx.y;
    int tid = threadIdx.x;
    int w    = tid >> 6;          // 0..3
    int g    = w >> 1;            // 0 -> f1 (Wh1), 1 -> f2 (WA, WB)
    int nh   = w & 1;             // n-half
    int lane = tid & 63;
    int l15  = lane & 15;
    int kg   = lane >> 4;

    int spoff[3];
    #pragma unroll
    for (int nl = 0; nl < 3; ++nl) {
        int p = (nh*3 + nl)*16 + l15;
        int sp = (p < PP) ? p : 81;
        spoff[nl] = sp*32 + ((kg ^ ((sp >> 1) & 3)) << 3);
    }

    f32x4 acc[6][3];
    #pragma unroll
    for (int m = 0; m < 6; ++m)
        #pragma unroll
        for (int nl = 0; nl < 3; ++nl)
            acc[m][nl] = (f32x4){0.f,0.f,0.f,0.f};

    const __hip_bfloat16* xb = xT2 + (size_t)b*24*CHW;
    const __hip_bfloat16* yb = yT2 + (size_t)b*2*CHW;
    const __hip_bfloat16* Wsel = g ? WAp : Wh1p;
    int otb = oy*6;

    for (int ch = 0; ch < 24; ++ch) {
        const __hip_bfloat16* cb = xb + (size_t)ch*CHW;
        short8v bf[3];
        #pragma unroll
        for (int nl = 0; nl < 3; ++nl)
            bf[nl] = *(const short8v*)&cb[spoff[nl]];
        short8v a[6];
        #pragma unroll
        for (int m = 0; m < 6; ++m)
            a[m] = *(const short8v*)(Wsel + ((((size_t)(otb + m))*24 + ch) << 9) + (lane<<3));
        #pragma unroll
        for (int nl = 0; nl < 3; ++nl)
            #pragma unroll
            for (int m = 0; m < 6; ++m)
                acc[m][nl] = __builtin_amdgcn_mfma_f32_16x16x32_bf16(a[m], bf[nl], acc[m][nl], 0, 0, 0);
    }

    if (g == 1) {
        for (int ch2 = 0; ch2 < 2; ++ch2) {
            const __hip_bfloat16* cb = yb + (size_t)ch2*CHW;
            short8v bf[3];
            #pragma unroll
            for (int nl = 0; nl < 3; ++nl)
                bf[nl] = *(const short8v*)&cb[spoff[nl]];
            short8v a[6];
            #pragma unroll
            for (int m = 0; m < 6; ++m)
                a[m] = *(const short8v*)(WBp + ((((size_t)(otb + m))*2 + ch2) << 9) + (lane<<3));
            #pragma unroll
            for (int nl = 0; nl < 3; ++nl)
                #pragma unroll
                for (int m = 0; m < 6; ++m)
                    acc[m][nl] = __builtin_amdgcn_mfma_f32_16x16x32_bf16(a[m], bf[nl], acc[m][nl], 0, 0, 0);
        }
    }

    __hip_bfloat16* dst = g ? f2 : f1;
    const float* bias = g ? beff : bh1;
    #pragma unroll
    for (int m = 0; m < 6; ++m) {
        #pragma unroll
        for (int r = 0; r < 4; ++r) {
            int o = (otb + m)*16 + kg*4 + r;
            float bb = bias[o];
            #pragma unroll
            for (int nl = 0; nl < 3; ++nl) {
                int p = (nh*3 + nl)*16 + l15;
                if (p < PP)
                    dst[((size_t)b*CCH + o)*PP + p] = __float2bfloat16(acc[m][nl][r] + bb);
            }
        }
    }
}

// ---------------- FZ: 512 thr; cor sums + alpha/gamma + image build ---------
__global__ __launch_bounds__(512) void k_finalize(
    const __hip_bfloat16* __restrict__ f1, const __hip_bfloat16* __restrict__ f2,
    const float* __restrict__ f22, const float* __restrict__ ccs,
    const float* __restrict__ xw,
    __hip_bfloat16* __restrict__ inb2)
{
    int b = blockIdx.x;
    int tid = threadIdx.x;
    __shared__ float red[486][5];
    __shared__ float sal[81], sga[81], scm[81];
    __shared__ float ls[64][82];
    // zero row 81 of every chunk
    for (int i = tid; i < 24*32; i += 512) {
        int ch = i >> 5, c = i & 31;
        inb2[(((size_t)b*24 + ch)*96 + 81)*32 + c] = __float2bfloat16(0.f);
    }
    bool act = tid < 486;
    float Sxx=0.f, Syy=0.f, Sxy=0.f, Sx=0.f, Sy=0.f;
    const __hip_bfloat16* A = f1 + (size_t)b*CCH*PP;
    const __hip_bfloat16* C = f2 + (size_t)b*CCH*PP;
    if (act) {
        for (int c0 = 0; c0 < CCH; c0 += 6) {
            float u = __bfloat162float(A[(size_t)c0*PP + tid]);
            float v = __bfloat162float(C[(size_t)c0*PP + tid]);
            Sxx = fmaf(u,u,Sxx); Syy = fmaf(v,v,Syy); Sxy = fmaf(u,v,Sxy);
            Sx += u; Sy += v;
        }
        red[tid][0]=Sxx; red[tid][1]=Syy; red[tid][2]=Sxy; red[tid][3]=Sx; red[tid][4]=Sy;
    }
    __syncthreads();
    if (tid < 81) {
        float xx=0.f, yy=0.f, xy=0.f, sx=0.f, sy=0.f;
        #pragma unroll
        for (int k = 0; k < 6; ++k) {
            xx += red[tid+81*k][0];
            yy += red[tid+81*k][1];
            xy += red[tid+81*k][2];
            sx += red[tid+81*k][3];
            sy += red[tid+81*k][4];
        }
        float cor1 = xy / fmaxf(sqrtf(xx)*sqrtf(yy), 1e-8f);
        float al = 0.5f*(1.f - cor1);
        float sum21 = sx + al*sy;
        float n21 = sqrtf(fmaxf(xx + 2.f*al*xy + al*al*yy, 0.f));
        int t = b*81 + tid;
        float fv = f22[t];
        float cor2 = (fv * sum21) / fmaxf(n21 * 27.712812921102035f * fabsf(fv), 1e-8f);
        float be = 0.5f*(1.f - cor2 + ccs[t]);
        sal[tid] = al;
        sga[tid] = be * fv;
        scm[tid] = 1.f + xw[t];
    }
    for (int c0 = 0; c0 < CCH; c0 += 64) {
        int ch0 = c0 >> 5;
        __syncthreads();
        for (int i = tid; i < 64*81; i += 512) {
            int c = i / 81, p = i - c*81;
            size_t gidx = ((size_t)b*CCH + c0 + c)*PP + p;
            float u = __bfloat162float(f1[gidx]);
            float v = __bfloat162float(f2[gidx]);
            ls[c][p] = scm[p]*(u + sal[p]*v + sga[p]);
        }
        __syncthreads();
        for (int i = tid; i < 81*64; i += 512) {
            int p = i >> 6, c = i & 63;
            int ch = ch0 + (c >> 5), cc = c & 31;
            int s = cc >> 3, j = cc & 7;
            int slot = s ^ ((p >> 1) & 3);
            inb2[(((size_t)b*24 + ch)*96 + p)*32 + slot*8 + j] = __float2bfloat16(ls[c][p]);
        }
    }
}

// ---------------- KB (R12-exact): bconv MFMA, 2 batches/block, 3-chunk groups
__global__ __launch_bounds__(256, 2) void k_bconv_mfma(
    const __hip_bfloat16* __restrict__ inb2,  // [B][24][96][32] swizzled image
    const __hip_bfloat16* __restrict__ Wp,    // packed [9][48][24][512]
    const float* __restrict__ bn_g, const float* __restrict__ bn_b,
    const float* __restrict__ bn_m, const float* __restrict__ bn_v,
    float* __restrict__ out)
{
    int oy = blockIdx.x;        // 0..7, o-extent 96; XCD = linear%8 = oy
    int b0 = blockIdx.y * 2;
    int tid = threadIdx.x;
    int w    = tid >> 6;        // 0..3
    int bi   = w >> 1;          // batch within pair
    int nh   = w & 1;           // n-half -> n-tiles {3*nh..3*nh+2}
    int lane = tid & 63;
    int l15  = lane & 15;
    int kg   = lane >> 4;

    __shared__ __align__(16) __hip_bfloat16 ls[6*CHW];   // [2 b][3 chunks][3072] = 36 KB

    int spoff[9][3];
    #pragma unroll
    for (int t = 0; t < 9; ++t) {
        int dy = t/3 - 1, dx = t%3 - 1;
        #pragma unroll
        for (int nl = 0; nl < 3; ++nl) {
            int p = (nh*3 + nl)*16 + l15;
            int yy = p/9, xx = p - yy*9;
            int Y = yy + dy, X = xx + dx;
            bool ok = (p < PP) && (Y >= 0) && (Y < 9) && (X >= 0) && (X < 9);
            int sp = ok ? (Y*9 + X) : 81;
            spoff[t][nl] = sp*32 + ((kg ^ ((sp >> 1) & 3)) << 3);
        }
    }

    f32x4 acc[6][3];
    #pragma unroll
    for (int m = 0; m < 6; ++m)
        #pragma unroll
        for (int nl = 0; nl < 3; ++nl)
            acc[m][nl] = (f32x4){0.f,0.f,0.f,0.f};

    const __hip_bfloat16* img0 = inb2 + (size_t)(b0    )*24*CHW;
    const __hip_bfloat16* img1 = inb2 + (size_t)(b0 + 1)*24*CHW;
    int otb = oy*6;

    for (int grp = 0; grp < 8; ++grp) {
        __syncthreads();
        // stage 3 chunks x 2 batches = 36 slabs of 1KB; 9 per wave
        #pragma unroll
        for (int k = 0; k < 9; ++k) {
            int it = w + 4*k;                 // 0..35
            int bb = it / 18;
            int r  = it - bb*18;
            int cc = r / 6, sub = r - cc*6;
            const __hip_bfloat16* src =
                (bb ? img1 : img0) + (size_t)(grp*3 + cc)*CHW + sub*512;
            GLL16(src + lane*8, &ls[(size_t)(bb*3 + cc)*CHW + sub*512]);
        }
        __syncthreads();
        for (int cc = 0; cc < 3; ++cc) {
            int ch = grp*3 + cc;
            const __hip_bfloat16* lb = &ls[(size_t)(bi*3 + cc)*CHW];
            #pragma unroll
            for (int t = 0; t < 9; ++t) {
                short8v a[6];
                #pragma unroll
                for (int m = 0; m < 6; ++m)
                    a[m] = *(const short8v*)(Wp + (((size_t)(t*48 + otb + m)*24 + ch) << 9) + (lane<<3));
                #pragma unroll
                for (int nl = 0; nl < 3; ++nl) {
                    short8v bf = *(const short8v*)&lb[spoff[t][nl]];
                    #pragma unroll
                    for (int m = 0; m < 6; ++m)
                        acc[m][nl] = __builtin_amdgcn_mfma_f32_16x16x32_bf16(a[m], bf, acc[m][nl], 0, 0, 0);
                }
            }
        }
    }

    int b = b0 + bi;
    #pragma unroll
    for (int m = 0; m < 6; ++m) {
        #pragma unroll
        for (int r = 0; r < 4; ++r) {
            int o = (otb + m)*16 + kg*4 + r;
            float sc = bn_g[o] * rsqrtf(bn_v[o] + 1e-5f);
            float mn = bn_m[o], bt = bn_b[o];
            #pragma unroll
            for (int nl = 0; nl < 3; ++nl) {
                int p = (nh*3 + nl)*16 + l15;
                if (p < PP) {
                    float v = (acc[m][nl][r] - mn) * sc + bt;
                    out[((size_t)b*CCH + o)*PP + p] = (v > 0.f) ? v : 0.01f*v;
                }
            }
        }
    }
}

extern "C" void kernel_launch(void* const* d_in, const int* in_sizes, int n_in,
                              void* d_out, int out_size, void* d_ws, size_t ws_size,
                              hipStream_t stream)
{
    (void)in_sizes; (void)n_in; (void)out_size; (void)ws_size;
    const float* x    = (const float*)d_in[0];
    const float* y    = (const float*)d_in[1];
    const float* Wh1  = (const float*)d_in[2];
    const float* bh1  = (const float*)d_in[3];
    const float* W11  = (const float*)d_in[4];
    const float* b11  = (const float*)d_in[5];
    const float* Wh2  = (const float*)d_in[6];
    const float* bh2  = (const float*)d_in[7];
    const float* Wl1  = (const float*)d_in[8];
    const float* bl1  = (const float*)d_in[9];
    const float* wh3  = (const float*)d_in[10];
    const float* bh3  = (const float*)d_in[11];
    const float* wl2  = (const float*)d_in[12];
    const float* bl2  = (const float*)d_in[13];
    const float* W12  = (const float*)d_in[14];
    const float* b12  = (const float*)d_in[15];
    const float* Wl3  = (const float*)d_in[16];
    const float* bl3  = (const float*)d_in[17];
    const float* wcc  = (const float*)d_in[18];
    const float* bcc  = (const float*)d_in[19];
    const float* wpool= (const float*)d_in[20];
    const float* bpool= (const float*)d_in[21];
    const float* Wfc1 = (const float*)d_in[22];
    const float* bfc1 = (const float*)d_in[23];
    const float* Wfc2 = (const float*)d_in[24];
    const float* bfc2 = (const float*)d_in[25];
    const float* Wb   = (const float*)d_in[26];
    const float* bng  = (const float*)d_in[27];
    const float* bnb  = (const float*)d_in[28];
    const float* bnm  = (const float*)d_in[29];
    const float* bnv  = (const float*)d_in[30];
    float* out = (float*)d_out;
    float* ws = (float*)d_ws;

    size_t off = 0;
    float* beff  = ws + off; off += CCH;
    float* f3    = ws + off; off += BATCH*2*PP;
    float* f4    = ws + off; off += BATCH*2*PP;
    float* Af    = ws + off; off += BATCH*10*PP;
    float* Uf    = ws + off; off += BATCH*10*PP;
    float* f22   = ws + off; off += BATCH*PP;
    float* ccs   = ws + off; off += BATCH*PP;
    float* xw    = ws + off; off += BATCH*PP;
    float* T1    = ws + off; off += 324*324;
    float* T2    = ws + off; off += 324*81;
    off = (off + 3) & ~(size_t)3;   // 16B-align bf16 region
    __hip_bfloat16* Wh1p = (__hip_bfloat16*)(ws + off); off += (size_t)48*24*512/2;
    __hip_bfloat16* WAp  = (__hip_bfloat16*)(ws + off); off += (size_t)48*24*512/2;
    __hip_bfloat16* WBp  = (__hip_bfloat16*)(ws + off); off += (size_t)48*2*512/2;
    __hip_bfloat16* yT2  = (__hip_bfloat16*)(ws + off); off += (size_t)BATCH*2*CHW/2;
    __hip_bfloat16* f1b  = (__hip_bfloat16*)(ws + off); off += (size_t)BATCH*CCH*PP/2;
    __hip_bfloat16* f2b  = (__hip_bfloat16*)(ws + off); off += (size_t)BATCH*CCH*PP/2;
    off = (off + 3) & ~(size_t)3;
    __hip_bfloat16* inb2 = (__hip_bfloat16*)(ws + off); off += (size_t)BATCH*24*CHW/2;
    __hip_bfloat16* Wp   = (__hip_bfloat16*)(ws + off); off += (size_t)9*48*24*512/2;
    // xT2 aliases inb2: fuse12 consumes xT2 before k_finalize overwrites it
    __hip_bfloat16* xT2 = inb2;

    k_prep<<<dim3(CCH + 288 + 411), dim3(256), 0, stream>>>(
        W11, Wh2, Wl1, bh2, bl1, b11, Wh1, Wb, Wfc1, Wfc2,
        WAp, WBp, Wh1p, beff, Wp, T1, T2);
    k_xprep_f34<<<dim3(BATCH), dim3(512), 0, stream>>>(x, y, wh3, bh3, wl2, bl2, W12, b12, Wl3, bl3, xT2, yT2, f3, f4, Af);
    k_ssim_b2<<<dim3(102), dim3(256), 0, stream>>>(Af, Uf);
    k_fc<<<dim3(BATCH), dim3(256), 0, stream>>>(Uf, f3, f4, wcc, bcc, wpool, bpool, T1, bfc1, T2, bfc2, f22, ccs, xw);
    k_fuse12_mfma<<<dim3(8, BATCH), dim3(256), 0, stream>>>(xT2, yT2, Wh1p, WAp, WBp, bh1, beff, f1b, f2b);
    k_finalize<<<dim3(BATCH), dim3(512), 0, stream>>>(f1b, f2b, f22, ccs, xw, inb2);
    k_bconv_mfma<<<dim3(8, BATCH/2), dim3(256), 0, stream>>>(inb2, Wp, bng, bnb, bnm, bnv, out);
}

// Round 18
// 675.328 us; speedup vs baseline: 1.3464x; 1.0132x over previous
//
#include <hip/hip_runtime.h>
#include <hip/hip_bf16.h>
#include <math.h>

#define BATCH 256
#define CCH 768
#define LCH 64
#define PP 81
#define CHW 3072   // elems per chunk image: 96 rows x 32 ch

typedef __attribute__((ext_vector_type(8))) short short8v;
typedef __attribute__((ext_vector_type(4))) float f32x4;

#define GLL16(gp, lp) __builtin_amdgcn_global_load_lds( \
    (const __attribute__((address_space(1))) void*)(gp), \
    (__attribute__((address_space(3))) void*)(lp), 16, 0, 0)

// ---------------- P: merged weight prep (compose + wprep + fcprep) ----------
__global__ __launch_bounds__(256) void k_prep(
    const float* __restrict__ W11, const float* __restrict__ Wh2,
    const float* __restrict__ Wl1, const float* __restrict__ bh2,
    const float* __restrict__ bl1, const float* __restrict__ b11,
    const float* __restrict__ Wh1, const float* __restrict__ Wb,
    const float* __restrict__ Wfc1, const float* __restrict__ Wfc2,
    __hip_bfloat16* __restrict__ WAp, __hip_bfloat16* __restrict__ WBp,
    __hip_bfloat16* __restrict__ Wh1p, float* __restrict__ beff,
    __hip_bfloat16* __restrict__ Wp,
    float* __restrict__ T1, float* __restrict__ T2)
{
    int blk = blockIdx.x;
    int t = threadIdx.x;
    if (blk < CCH) {
        int o = blk;
        int ot = o >> 4, l15o = o & 15;
        const float* w11row = W11 + (size_t)o * CCH;
        for (int c = t; c < CCH; c += 256) {
            float s = 0.f;
            for (int k = 0; k < 512; ++k) s = fmaf(w11row[k], Wh2[(size_t)k*CCH + c], s);
            int ch = c >> 5, kg = (c >> 3) & 3, j = c & 7;
            size_t idx = (((size_t)ot*24 + ch) << 9) + (size_t)(kg*16 + l15o)*8 + j;
            WAp[idx]  = __float2bfloat16(s);
            Wh1p[idx] = __float2bfloat16(Wh1[(size_t)o*CCH + c]);
        }
        if (t < LCH) {
            float s = 0.f;
            for (int k = 0; k < 256; ++k) s = fmaf(w11row[512+k], Wl1[k*LCH + t], s);
            int ch = t >> 5, kg = (t >> 3) & 3, j = t & 7;
            size_t idx = (((size_t)ot*2 + ch) << 9) + (size_t)(kg*16 + l15o)*8 + j;
            WBp[idx] = __float2bfloat16(s);
        }
        if (t == 0) {
            float s = b11[o];
            for (int k = 0; k < 512; ++k) s = fmaf(w11row[k], bh2[k], s);
            for (int k = 0; k < 256; ++k) s = fmaf(w11row[512+k], bl1[k], s);
            beff[o] = s;
        }
    } else if (blk < CCH + 288) {
        int id = blk - CCH;
        int ot = id / 6;
        int i  = (id - ot*6)*256 + t;
        int oi = i / 96, c8 = i - oi*96;
        const float* src = Wb + ((size_t)(ot*16 + oi)*CCH + c8*8)*9;
        int ch = c8 >> 2;
        int lane8 = (((c8 & 3)*16) + oi)*8;
        #pragma unroll
        for (int tt = 0; tt < 9; ++tt) {
            short8v v;
            #pragma unroll
            for (int j = 0; j < 8; ++j) {
                __hip_bfloat16 h = __float2bfloat16(src[j*9 + tt]);
                v[j] = __builtin_bit_cast(short, h);
            }
            *(short8v*)(Wp + ((((size_t)(tt*48 + ot))*24 + ch) << 9) + lane8) = v;
        }
    } else {
        int n = (blk - CCH - 288)*256 + t;
        if (n < 324*324) { int i = n / 324, j = n - i*324; T1[(size_t)j*324 + i] = Wfc1[n]; }
        if (n < 81*324)  { int q = n / 324, j = n - q*324; T2[(size_t)j*81 + q]  = Wfc2[n]; }
    }
}

// ---------------- XP: 512 thr; x,y -> swizzled images; fuse34 + ssim_wh -----
__global__ __launch_bounds__(512) void k_xprep_f34(
    const float* __restrict__ x, const float* __restrict__ y,
    const float* __restrict__ wh3, const float* __restrict__ bh3,
    const float* __restrict__ wl2, const float* __restrict__ bl2,
    const float* __restrict__ W12, const float* __restrict__ b12,
    const float* __restrict__ Wl3, const float* __restrict__ bl3,
    __hip_bfloat16* __restrict__ xT2, __hip_bfloat16* __restrict__ yT2,
    float* __restrict__ f3, float* __restrict__ f4, float* __restrict__ Af)
{
    int b = blockIdx.x;
    int tid = threadIdx.x;
    __shared__ float ls[64][82];
    __shared__ float red[486][4];
    __shared__ float zz[10][81];
    __shared__ float tb[10][81];
    int q = tid / 81, p81 = tid - q*81;
    bool act = tid < 486;
    // zero row 81 of every chunk (pad rows 82..95 never read)
    for (int i = tid; i < 24*32; i += 512) {
        int ch = i >> 5, c = i & 31;
        xT2[(((size_t)b*24 + ch)*96 + 81)*32 + c] = __float2bfloat16(0.f);
    }
    if (tid < 2*32) {
        int ch = tid >> 5, c = tid & 31;
        yT2[(((size_t)b*2 + ch)*96 + 81)*32 + c] = __float2bfloat16(0.f);
    }
    float sx = 0.f;
    for (int c0 = 0; c0 < CCH; c0 += 64) {
        int ch0 = c0 >> 5;
        __syncthreads();
        for (int i = tid; i < 64*81; i += 512) {
            int c = i / 81, p = i - c*81;
            ls[c][p] = x[((size_t)b*CCH + c0 + c)*PP + p];
        }
        __syncthreads();
        for (int i = tid; i < 81*64; i += 512) {
            int p = i >> 6, c = i & 63;
            int ch = ch0 + (c >> 5), cc = c & 31;
            int s = cc >> 3, j = cc & 7;
            int slot = s ^ ((p >> 1) & 3);
            xT2[(((size_t)b*24 + ch)*96 + p)*32 + slot*8 + j] = __float2bfloat16(ls[c][p]);
        }
        if (act)
            for (int c = q; c < 64; c += 6)
                sx = fmaf(wh3[c0+c], ls[c][p81], sx);
    }
    __syncthreads();
    for (int i = tid; i < 64*81; i += 512) {
        int c = i / 81, p = i - c*81;
        ls[c][p] = y[((size_t)b*LCH + c)*PP + p];
    }
    __syncthreads();
    for (int i = tid; i < 81*64; i += 512) {
        int p = i >> 6, c = i & 63;
        int ch = c >> 5, cc = c & 31;
        int s = cc >> 3, j = cc & 7;
        int slot = s ^ ((p >> 1) & 3);
        yT2[(((size_t)b*2 + ch)*96 + p)*32 + slot*8 + j] = __float2bfloat16(ls[c][p]);
    }
    float sy = 0.f, s40 = 0.f, s41 = 0.f;
    if (act) {
        for (int c = q; c < 64; c += 6) {
            float v = ls[c][p81];
            sy  = fmaf(wl2[c], v, sy);
            s40 = fmaf(Wl3[c], v, s40);
            s41 = fmaf(Wl3[LCH+c], v, s41);
        }
        red[tid][0]=sx; red[tid][1]=sy; red[tid][2]=s40; red[tid][3]=s41;
    }
    __syncthreads();
    if (tid < 81) {
        float SX = 0.f, SY = 0.f, S40 = 0.f, S41 = 0.f;
        #pragma unroll
        for (int k = 0; k < 6; ++k) {
            SX  += red[tid+81*k][0];
            SY  += red[tid+81*k][1];
            S40 += red[tid+81*k][2];
            S41 += red[tid+81*k][3];
        }
        float t3a = SX + bh3[0];
        float t3b = SY + bl2[0];
        float f30 = W12[0]*t3a + W12[1]*t3b + b12[0];
        float f31 = W12[2]*t3a + W12[3]*t3b + b12[1];
        float f40 = S40 + bl3[0];
        float f41 = S41 + bl3[1];
        f3[(b*2+0)*PP+tid] = f30; f3[(b*2+1)*PP+tid] = f31;
        f4[(b*2+0)*PP+tid] = f40; f4[(b*2+1)*PP+tid] = f41;
        zz[0][tid]=f30; zz[1][tid]=f40; zz[2][tid]=f30*f30; zz[3][tid]=f40*f40; zz[4][tid]=f30*f40;
        zz[5][tid]=f31; zz[6][tid]=f41; zz[7][tid]=f31*f31; zz[8][tid]=f41*f41; zz[9][tid]=f31*f41;
    }
    __syncthreads();
    for (int i = tid; i < 10*81; i += 512) {
        int f = i / 81, p = i - f*81;
        int yy = p/9, xx = p - yy*9;
        float s = 0.f;
        #pragma unroll
        for (int d = -3; d <= 3; ++d) {
            int j = xx + d;
            j = (j < 0) ? (-1-j) : ((j > 8) ? (17-j) : j);
            s += zz[f][yy*9+j];
        }
        tb[f][p] = s * (1.f/7.f);
    }
    __syncthreads();
    for (int i = tid; i < 10*81; i += 512) {
        int f = i / 81, p = i - f*81;
        int yy = p/9, xx = p - yy*9;
        float s = 0.f;
        #pragma unroll
        for (int d = -3; d <= 3; ++d) {
            int j = yy + d;
            j = (j < 0) ? (-1-j) : ((j > 8) ? (17-j) : j);
            s += tb[f][j*9+xx];
        }
        Af[((size_t)b*10 + f)*81 + p] = s * (1.f/7.f);
    }
}

// ---------------- S3: box-7 along batch, 8 cols/block, grid 102 -------------
__global__ __launch_bounds__(256) void k_ssim_b2(
    const float* __restrict__ A, float* __restrict__ U)
{
    int col0 = blockIdx.x * 8;
    int tid = threadIdx.x;
    __shared__ float lsb[256][9];
    for (int i = tid; i < 256*8; i += 256) {
        int j = i >> 3, cc = i & 7;
        int col = col0 + cc;
        lsb[j][cc] = (col < 810) ? A[(size_t)j*810 + col] : 0.f;
    }
    __syncthreads();
    for (int i = tid; i < 256*8; i += 256) {
        int b = i >> 3, cc = i & 7;
        float s = 0.f;
        #pragma unroll
        for (int d = -3; d <= 3; ++d) {
            int j = b + d;
            j = (j < 0) ? (-1-j) : ((j > 255) ? (511-j) : j);
            s += lsb[j][cc];
        }
        int col = col0 + cc;
        if (col < 810) U[(size_t)b*810 + col] = s * (1.f/7.f);
    }
}

// ---------------- F: 256 thr; ssim_comb + pool + fc1(gelu) + fc2(leaky) -----
__global__ __launch_bounds__(256) void k_fc(
    const float* __restrict__ U, const float* __restrict__ f3,
    const float* __restrict__ f4, const float* __restrict__ wcc,
    const float* __restrict__ bcc,
    const float* __restrict__ wpool, const float* __restrict__ bpool,
    const float* __restrict__ T1, const float* __restrict__ bfc1,
    const float* __restrict__ T2, const float* __restrict__ bfc2,
    float* __restrict__ f22, float* __restrict__ ccs,
    float* __restrict__ xw)
{
    int b = blockIdx.x;
    int tid = threadIdx.x;
    __shared__ float xc[324];
    __shared__ float h1[324];
    __shared__ float pr[2][81], ps[2][81];
    const float cov = 343.f/342.f, C1c = 1e-4f, C2c = 9e-4f;
    for (int i = tid; i < 162; i += 256) {
        int k = i / 81, p = i - k*81;
        const float* u = U + (size_t)b*810 + (k*5)*81 + p;
        float ux = u[0], uy = u[81], uxx = u[162], uyy = u[243], uxy = u[324];
        float vx = cov*(uxx - ux*ux), vy = cov*(uyy - uy*uy), vxy = cov*(uxy - ux*uy);
        float S = ((2.f*ux*uy + C1c)*(2.f*vxy + C2c)) /
                  ((ux*ux + uy*uy + C1c)*(vx + vy + C2c));
        float a = f4[(b*2+k)*81+p] + S*f3[(b*2+k)*81+p];
        pr[k][p] = wcc[k]*a;
        ps[k][p] = wcc[k]*S;
    }
    __syncthreads();
    if (tid < 81) {
        float fv = pr[0][tid] + pr[1][tid] + bcc[0];
        float cv = ps[0][tid] + ps[1][tid] + bcc[0];
        f22[b*81+tid] = fv;
        ccs[b*81+tid] = cv;
        xc[tid] = fv; xc[243+tid] = fv;
    }
    __syncthreads();
    for (int i = tid; i < 162; i += 256) {
        int k = i / 81, p = i - k*81;
        int yy = p/9, xx = p - yy*9;
        float s = bpool[k];
        #pragma unroll
        for (int dy = -1; dy <= 1; ++dy)
            #pragma unroll
            for (int dx = -1; dx <= 1; ++dx) {
                int Y = yy+dy, X = xx+dx;
                if (Y >= 0 && Y < 9 && X >= 0 && X < 9)
                    s = fmaf(wpool[k*9 + (dy+1)*3 + (dx+1)], xc[Y*9+X], s);
            }
        xc[81+i] = s;
    }
    __syncthreads();
    for (int i = tid; i < 324; i += 256) {
        float s = bfc1[i];
        for (int j = 0; j < 324; ++j) s = fmaf(T1[(size_t)j*324 + i], xc[j], s);
        h1[i] = 0.5f*s*(1.f + erff(s*0.70710678118654752f));
    }
    __syncthreads();
    for (int qq = tid; qq < 81; qq += 256) {
        float s = bfc2[qq];
        for (int j = 0; j < 324; ++j) s = fmaf(T2[(size_t)j*81 + qq], h1[j], s);
        xw[b*81+qq] = (s > 0.f) ? s : 0.01f*s;
    }
}

// ---------------- K1 v11: fuse12 MFMA, 2 batches/block, direct-global -------
__global__ __launch_bounds__(512) void k_fuse12_mfma(
    const __hip_bfloat16* __restrict__ xT2,   // [B][24][96][32] swizzled image
    const __hip_bfloat16* __restrict__ yT2,   // [B][2][96][32]
    const __hip_bfloat16* __restrict__ Wh1p,
    const __hip_bfloat16* __restrict__ WAp,
    const __hip_bfloat16* __restrict__ WBp,
    const float* __restrict__ bh1, const float* __restrict__ beff,
    __hip_bfloat16* __restrict__ f1, __hip_bfloat16* __restrict__ f2)
{
    int oy = blockIdx.x;          // 0..7, o-extent 96; XCD = linear%8 = oy
    int b0 = blockIdx.y * 2;
    int tid = threadIdx.x;
    int w    = tid >> 6;          // 0..7
    int bi   = w >> 2;            // batch within pair
    int g    = (w >> 1) & 1;      // 0 -> f1 (Wh1), 1 -> f2 (WA, WB)
    int nh   = w & 1;             // n-half
    int lane = tid & 63;
    int l15  = lane & 15;
    int kg   = lane >> 4;

    int spoff[3];
    #pragma unroll
    for (int nl = 0; nl < 3; ++nl) {
        int p = (nh*3 + nl)*16 + l15;
        int sp = (p < PP) ? p : 81;
        spoff[nl] = sp*32 + ((kg ^ ((sp >> 1) & 3)) << 3);
    }

    f32x4 acc[6][3];
    #pragma unroll
    for (int m = 0; m < 6; ++m)
        #pragma unroll
        for (int nl = 0; nl < 3; ++nl)
            acc[m][nl] = (f32x4){0.f,0.f,0.f,0.f};

    int b = b0 + bi;
    const __hip_bfloat16* xb = xT2 + (size_t)b*24*CHW;
    const __hip_bfloat16* yb = yT2 + (size_t)b*2*CHW;
    const __hip_bfloat16* Wsel = g ? WAp : Wh1p;
    int otb = oy*6;

    for (int ch = 0; ch < 24; ++ch) {
        const __hip_bfloat16* cb = xb + (size_t)ch*CHW;
        short8v bf[3];
        #pragma unroll
        for (int nl = 0; nl < 3; ++nl)
            bf[nl] = *(const short8v*)&cb[spoff[nl]];
        short8v a[6];
        #pragma unroll
        for (int m = 0; m < 6; ++m)
            a[m] = *(const short8v*)(Wsel + ((((size_t)(otb + m))*24 + ch) << 9) + (lane<<3));
        #pragma unroll
        for (int nl = 0; nl < 3; ++nl)
            #pragma unroll
            for (int m = 0; m < 6; ++m)
                acc[m][nl] = __builtin_amdgcn_mfma_f32_16x16x32_bf16(a[m], bf[nl], acc[m][nl], 0, 0, 0);
    }

    if (g == 1) {
        for (int ch2 = 0; ch2 < 2; ++ch2) {
            const __hip_bfloat16* cb = yb + (size_t)ch2*CHW;
            short8v bf[3];
            #pragma unroll
            for (int nl = 0; nl < 3; ++nl)
                bf[nl] = *(const short8v*)&cb[spoff[nl]];
            short8v a[6];
            #pragma unroll
            for (int m = 0; m < 6; ++m)
                a[m] = *(const short8v*)(WBp + ((((size_t)(otb + m))*2 + ch2) << 9) + (lane<<3));
            #pragma unroll
            for (int nl = 0; nl < 3; ++nl)
                #pragma unroll
                for (int m = 0; m < 6; ++m)
                    acc[m][nl] = __builtin_amdgcn_mfma_f32_16x16x32_bf16(a[m], bf[nl], acc[m][nl], 0, 0, 0);
        }
    }

    __hip_bfloat16* dst = g ? f2 : f1;
    const float* bias = g ? beff : bh1;
    #pragma unroll
    for (int m = 0; m < 6; ++m) {
        #pragma unroll
        for (int r = 0; r < 4; ++r) {
            int o = (otb + m)*16 + kg*4 + r;
            float bb = bias[o];
            #pragma unroll
            for (int nl = 0; nl < 3; ++nl) {
                int p = (nh*3 + nl)*16 + l15;
                if (p < PP)
                    dst[((size_t)b*CCH + o)*PP + p] = __float2bfloat16(acc[m][nl][r] + bb);
            }
        }
    }
}

// ---------------- FZ: 512 thr; cor sums + alpha/gamma + image build ---------
__global__ __launch_bounds__(512) void k_finalize(
    const __hip_bfloat16* __restrict__ f1, const __hip_bfloat16* __restrict__ f2,
    const float* __restrict__ f22, const float* __restrict__ ccs,
    const float* __restrict__ xw,
    __hip_bfloat16* __restrict__ inb2)
{
    int b = blockIdx.x;
    int tid = threadIdx.x;
    __shared__ float red[486][5];
    __shared__ float sal[81], sga[81], scm[81];
    __shared__ float ls[64][82];
    // zero row 81 of every chunk
    for (int i = tid; i < 24*32; i += 512) {
        int ch = i >> 5, c = i & 31;
        inb2[(((size_t)b*24 + ch)*96 + 81)*32 + c] = __float2bfloat16(0.f);
    }
    bool act = tid < 486;
    float Sxx=0.f, Syy=0.f, Sxy=0.f, Sx=0.f, Sy=0.f;
    const __hip_bfloat16* A = f1 + (size_t)b*CCH*PP;
    const __hip_bfloat16* C = f2 + (size_t)b*CCH*PP;
    if (act) {
        for (int c0 = 0; c0 < CCH; c0 += 6) {
            float u = __bfloat162float(A[(size_t)c0*PP + tid]);
            float v = __bfloat162float(C[(size_t)c0*PP + tid]);
            Sxx = fmaf(u,u,Sxx); Syy = fmaf(v,v,Syy); Sxy = fmaf(u,v,Sxy);
            Sx += u; Sy += v;
        }
        red[tid][0]=Sxx; red[tid][1]=Syy; red[tid][2]=Sxy; red[tid][3]=Sx; red[tid][4]=Sy;
    }
    __syncthreads();
    if (tid < 81) {
        float xx=0.f, yy=0.f, xy=0.f, sx=0.f, sy=0.f;
        #pragma unroll
        for (int k = 0; k < 6; ++k) {
            xx += red[tid+81*k][0];
            yy += red[tid+81*k][1];
            xy += red[tid+81*k][2];
            sx += red[tid+81*k][3];
            sy += red[tid+81*k][4];
        }
        float cor1 = xy / fmaxf(sqrtf(xx)*sqrtf(yy), 1e-8f);
        float al = 0.5f*(1.f - cor1);
        float sum21 = sx + al*sy;
        float n21 = sqrtf(fmaxf(xx + 2.f*al*xy + al*al*yy, 0.f));
        int t = b*81 + tid;
        float fv = f22[t];
        float cor2 = (fv * sum21) / fmaxf(n21 * 27.712812921102035f * fabsf(fv), 1e-8f);
        float be = 0.5f*(1.f - cor2 + ccs[t]);
        sal[tid] = al;
        sga[tid] = be * fv;
        scm[tid] = 1.f + xw[t];
    }
    for (int c0 = 0; c0 < CCH; c0 += 64) {
        int ch0 = c0 >> 5;
        __syncthreads();
        for (int i = tid; i < 64*81; i += 512) {
            int c = i / 81, p = i - c*81;
            size_t gidx = ((size_t)b*CCH + c0 + c)*PP + p;
            float u = __bfloat162float(f1[gidx]);
            float v = __bfloat162float(f2[gidx]);
            ls[c][p] = scm[p]*(u + sal[p]*v + sga[p]);
        }
        __syncthreads();
        for (int i = tid; i < 81*64; i += 512) {
            int p = i >> 6, c = i & 63;
            int ch = ch0 + (c >> 5), cc = c & 31;
            int s = cc >> 3, j = cc & 7;
            int slot = s ^ ((p >> 1) & 3);
            inb2[(((size_t)b*24 + ch)*96 + p)*32 + slot*8 + j] = __float2bfloat16(ls[c][p]);
        }
    }
}

// ---------------- KB v12: bconv MFMA, 4 batches/block, 3-chunk groups -------
__global__ __launch_bounds__(512, 2) void k_bconv_mfma(
    const __hip_bfloat16* __restrict__ inb2,  // [B][24][96][32] swizzled image
    const __hip_bfloat16* __restrict__ Wp,    // packed [9][48][24][512]
    const float* __restrict__ bn_g, const float* __restrict__ bn_b,
    const float* __restrict__ bn_m, const float* __restrict__ bn_v,
    float* __restrict__ out)
{
    int oy = blockIdx.x;        // 0..7, o-extent 96; XCD = linear%8 = oy
    int b0 = blockIdx.y * 4;
    int tid = threadIdx.x;
    int w    = tid >> 6;        // 0..7
    int bi   = w >> 1;          // batch within quad (0..3)
    int nh   = w & 1;           // n-half -> n-tiles {3*nh..3*nh+2}
    int lane = tid & 63;
    int l15  = lane & 15;
    int kg   = lane >> 4;

    __shared__ __align__(16) __hip_bfloat16 ls[12*CHW];  // [4 b][3 chunks] = 72 KB

    int spoff[9][3];
    #pragma unroll
    for (int t = 0; t < 9; ++t) {
        int dy = t/3 - 1, dx = t%3 - 1;
        #pragma unroll
        for (int nl = 0; nl < 3; ++nl) {
            int p = (nh*3 + nl)*16 + l15;
            int yy = p/9, xx = p - yy*9;
            int Y = yy + dy, X = xx + dx;
            bool ok = (p < PP) && (Y >= 0) && (Y < 9) && (X >= 0) && (X < 9);
            int sp = ok ? (Y*9 + X) : 81;
            spoff[t][nl] = sp*32 + ((kg ^ ((sp >> 1) & 3)) << 3);
        }
    }

    f32x4 acc[6][3];
    #pragma unroll
    for (int m = 0; m < 6; ++m)
        #pragma unroll
        for (int nl = 0; nl < 3; ++nl)
            acc[m][nl] = (f32x4){0.f,0.f,0.f,0.f};

    const __hip_bfloat16* imgs = inb2 + (size_t)b0*24*CHW;
    int otb = oy*6;

    for (int grp = 0; grp < 8; ++grp) {
        __syncthreads();
        // stage 3 chunks x 4 batches = 72 slabs of 1KB; 9 per wave
        #pragma unroll
        for (int k = 0; k < 9; ++k) {
            int it = w + 8*k;                 // 0..71
            int bb = it / 18;
            int r  = it - bb*18;
            int cc = r / 6, sub = r - cc*6;
            const __hip_bfloat16* src =
                imgs + ((size_t)bb*24 + grp*3 + cc)*CHW + sub*512;
            GLL16(src + lane*8, &ls[(size_t)(bb*3 + cc)*CHW + sub*512]);
        }
        __syncthreads();
        for (int cc = 0; cc < 3; ++cc) {
            int ch = grp*3 + cc;
            const __hip_bfloat16* lb = &ls[(size_t)(bi*3 + cc)*CHW];
            #pragma unroll
            for (int t = 0; t < 9; ++t) {
                short8v a[6];
                #pragma unroll
                for (int m = 0; m < 6; ++m)
                    a[m] = *(const short8v*)(Wp + (((size_t)(t*48 + otb + m)*24 + ch) << 9) + (lane<<3));
                #pragma unroll
                for (int nl = 0; nl < 3; ++nl) {
                    short8v bf = *(const short8v*)&lb[spoff[t][nl]];
                    #pragma unroll
                    for (int m = 0; m < 6; ++m)
                        acc[m][nl] = __builtin_amdgcn_mfma_f32_16x16x32_bf16(a[m], bf, acc[m][nl], 0, 0, 0);
                }
            }
        }
    }

    int b = b0 + bi;
    #pragma unroll
    for (int m = 0; m < 6; ++m) {
        #pragma unroll
        for (int r = 0; r < 4; ++r) {
            int o = (otb + m)*16 + kg*4 + r;
            float sc = bn_g[o] * rsqrtf(bn_v[o] + 1e-5f);
            float mn = bn_m[o], bt = bn_b[o];
            #pragma unroll
            for (int nl = 0; nl < 3; ++nl) {
                int p = (nh*3 + nl)*16 + l15;
                if (p < PP) {
                    float v = (acc[m][nl][r] - mn) * sc + bt;
                    out[((size_t)b*CCH + o)*PP + p] = (v > 0.f) ? v : 0.01f*v;
                }
            }
        }
    }
}

extern "C" void kernel_launch(void* const* d_in, const int* in_sizes, int n_in,
                              void* d_out, int out_size, void* d_ws, size_t ws_size,
                              hipStream_t stream)
{
    (void)in_sizes; (void)n_in; (void)out_size; (void)ws_size;
    const float* x    = (const float*)d_in[0];
    const float* y    = (const float*)d_in[1];
    const float* Wh1  = (const float*)d_in[2];
    const float* bh1  = (const float*)d_in[3];
    const float* W11  = (const float*)d_in[4];
    const float* b11  = (const float*)d_in[5];
    const float* Wh2  = (const float*)d_in[6];
    const float* bh2  = (const float*)d_in[7];
    const float* Wl1  = (const float*)d_in[8];
    const float* bl1  = (const float*)d_in[9];
    const float* wh3  = (const float*)d_in[10];
    const float* bh3  = (const float*)d_in[11];
    const float* wl2  = (const float*)d_in[12];
    const float* bl2  = (const float*)d_in[13];
    const float* W12  = (const float*)d_in[14];
    const float* b12  = (const float*)d_in[15];
    const float* Wl3  = (const float*)d_in[16];
    const float* bl3  = (const float*)d_in[17];
    const float* wcc  = (const float*)d_in[18];
    const float* bcc  = (const float*)d_in[19];
    const float* wpool= (const float*)d_in[20];
    const float* bpool= (const float*)d_in[21];
    const float* Wfc1 = (const float*)d_in[22];
    const float* bfc1 = (const float*)d_in[23];
    const float* Wfc2 = (const float*)d_in[24];
    const float* bfc2 = (const float*)d_in[25];
    const float* Wb   = (const float*)d_in[26];
    const float* bng  = (const float*)d_in[27];
    const float* bnb  = (const float*)d_in[28];
    const float* bnm  = (const float*)d_in[29];
    const float* bnv  = (const float*)d_in[30];
    float* out = (float*)d_out;
    float* ws = (float*)d_ws;

    size_t off = 0;
    float* beff  = ws + off; off += CCH;
    float* f3    = ws + off; off += BATCH*2*PP;
    float* f4    = ws + off; off += BATCH*2*PP;
    float* Af    = ws + off; off += BATCH*10*PP;
    float* Uf    = ws + off; off += BATCH*10*PP;
    float* f22   = ws + off; off += BATCH*PP;
    float* ccs   = ws + off; off += BATCH*PP;
    float* xw    = ws + off; off += BATCH*PP;
    float* T1    = ws + off; off += 324*324;
    float* T2    = ws + off; off += 324*81;
    off = (off + 3) & ~(size_t)3;   // 16B-align bf16 region
    __hip_bfloat16* Wh1p = (__hip_bfloat16*)(ws + off); off += (size_t)48*24*512/2;
    __hip_bfloat16* WAp  = (__hip_bfloat16*)(ws + off); off += (size_t)48*24*512/2;
    __hip_bfloat16* WBp  = (__hip_bfloat16*)(ws + off); off += (size_t)48*2*512/2;
    __hip_bfloat16* yT2  = (__hip_bfloat16*)(ws + off); off += (size_t)BATCH*2*CHW/2;
    __hip_bfloat16* f1b  = (__hip_bfloat16*)(ws + off); off += (size_t)BATCH*CCH*PP/2;
    __hip_bfloat16* f2b  = (__hip_bfloat16*)(ws + off); off += (size_t)BATCH*CCH*PP/2;
    off = (off + 3) & ~(size_t)3;
    __hip_bfloat16* inb2 = (__hip_bfloat16*)(ws + off); off += (size_t)BATCH*24*CHW/2;
    __hip_bfloat16* Wp   = (__hip_bfloat16*)(ws + off); off += (size_t)9*48*24*512/2;
    // xT2 aliases inb2: fuse12 consumes xT2 before k_finalize overwrites it
    __hip_bfloat16* xT2 = inb2;

    k_prep<<<dim3(CCH + 288 + 411), dim3(256), 0, stream>>>(
        W11, Wh2, Wl1, bh2, bl1, b11, Wh1, Wb, Wfc1, Wfc2,
        WAp, WBp, Wh1p, beff, Wp, T1, T2);
    k_xprep_f34<<<dim3(BATCH), dim3(512), 0, stream>>>(x, y, wh3, bh3, wl2, bl2, W12, b12, Wl3, bl3, xT2, yT2, f3, f4, Af);
    k_ssim_b2<<<dim3(102), dim3(256), 0, stream>>>(Af, Uf);
    k_fc<<<dim3(BATCH), dim3(256), 0, stream>>>(Uf, f3, f4, wcc, bcc, wpool, bpool, T1, bfc1, T2, bfc2, f22, ccs, xw);
    k_fuse12_mfma<<<dim3(8, BATCH/2), dim3(512), 0, stream>>>(xT2, yT2, Wh1p, WAp, WBp, bh1, beff, f1b, f2b);
    k_finalize<<<dim3(BATCH), dim3(512), 0, stream>>>(f1b, f2b, f22, ccs, xw, inb2);
    k_bconv_mfma<<<dim3(8, BATCH/4), dim3(512), 0, stream>>>(inb2, Wp, bng, bnb, bnm, bnv, out);
}

// Round 19
// 664.333 us; speedup vs baseline: 1.3687x; 1.0165x over previous
//
#include <hip/hip_runtime.h>
#include <hip/hip_bf16.h>
#include <math.h>

#define BATCH 256
#define CCH 768
#define LCH 64
#define PP 81
#define CHW 3072   // elems per chunk image: 96 rows x 32 ch

typedef __attribute__((ext_vector_type(8))) short short8v;
typedef __attribute__((ext_vector_type(4))) float f32x4;

#define GLL16(gp, lp) __builtin_amdgcn_global_load_lds( \
    (const __attribute__((address_space(1))) void*)(gp), \
    (__attribute__((address_space(3))) void*)(lp), 16, 0, 0)

// ---------------- P: merged weight prep (compose + wprep + fcprep) ----------
__global__ __launch_bounds__(256) void k_prep(
    const float* __restrict__ W11, const float* __restrict__ Wh2,
    const float* __restrict__ Wl1, const float* __restrict__ bh2,
    const float* __restrict__ bl1, const float* __restrict__ b11,
    const float* __restrict__ Wh1, const float* __restrict__ Wb,
    const float* __restrict__ Wfc1, const float* __restrict__ Wfc2,
    __hip_bfloat16* __restrict__ WAp, __hip_bfloat16* __restrict__ WBp,
    __hip_bfloat16* __restrict__ Wh1p, float* __restrict__ beff,
    __hip_bfloat16* __restrict__ Wp,
    float* __restrict__ T1, float* __restrict__ T2)
{
    int blk = blockIdx.x;
    int t = threadIdx.x;
    if (blk < CCH) {
        int o = blk;
        int ot = o >> 4, l15o = o & 15;
        const float* w11row = W11 + (size_t)o * CCH;
        for (int c = t; c < CCH; c += 256) {
            float s = 0.f;
            for (int k = 0; k < 512; ++k) s = fmaf(w11row[k], Wh2[(size_t)k*CCH + c], s);
            int ch = c >> 5, kg = (c >> 3) & 3, j = c & 7;
            size_t idx = (((size_t)ot*24 + ch) << 9) + (size_t)(kg*16 + l15o)*8 + j;
            WAp[idx]  = __float2bfloat16(s);
            Wh1p[idx] = __float2bfloat16(Wh1[(size_t)o*CCH + c]);
        }
        if (t < LCH) {
            float s = 0.f;
            for (int k = 0; k < 256; ++k) s = fmaf(w11row[512+k], Wl1[k*LCH + t], s);
            int ch = t >> 5, kg = (t >> 3) & 3, j = t & 7;
            size_t idx = (((size_t)ot*2 + ch) << 9) + (size_t)(kg*16 + l15o)*8 + j;
            WBp[idx] = __float2bfloat16(s);
        }
        if (t == 0) {
            float s = b11[o];
            for (int k = 0; k < 512; ++k) s = fmaf(w11row[k], bh2[k], s);
            for (int k = 0; k < 256; ++k) s = fmaf(w11row[512+k], bl1[k], s);
            beff[o] = s;
        }
    } else if (blk < CCH + 288) {
        int id = blk - CCH;
        int ot = id / 6;
        int i  = (id - ot*6)*256 + t;
        int oi = i / 96, c8 = i - oi*96;
        const float* src = Wb + ((size_t)(ot*16 + oi)*CCH + c8*8)*9;
        int ch = c8 >> 2;
        int lane8 = (((c8 & 3)*16) + oi)*8;
        #pragma unroll
        for (int tt = 0; tt < 9; ++tt) {
            short8v v;
            #pragma unroll
            for (int j = 0; j < 8; ++j) {
                __hip_bfloat16 h = __float2bfloat16(src[j*9 + tt]);
                v[j] = __builtin_bit_cast(short, h);
            }
            *(short8v*)(Wp + ((((size_t)(tt*48 + ot))*24 + ch) << 9) + lane8) = v;
        }
    } else {
        int n = (blk - CCH - 288)*256 + t;
        if (n < 324*324) { int i = n / 324, j = n - i*324; T1[(size_t)j*324 + i] = Wfc1[n]; }
        if (n < 81*324)  { int q = n / 324, j = n - q*324; T2[(size_t)j*81 + q]  = Wfc2[n]; }
    }
}

// ---------------- XP: 512 thr; x,y -> swizzled images; fuse34 + ssim_wh -----
__global__ __launch_bounds__(512) void k_xprep_f34(
    const float* __restrict__ x, const float* __restrict__ y,
    const float* __restrict__ wh3, const float* __restrict__ bh3,
    const float* __restrict__ wl2, const float* __restrict__ bl2,
    const float* __restrict__ W12, const float* __restrict__ b12,
    const float* __restrict__ Wl3, const float* __restrict__ bl3,
    __hip_bfloat16* __restrict__ xT2, __hip_bfloat16* __restrict__ yT2,
    float* __restrict__ f3, float* __restrict__ f4, float* __restrict__ Af)
{
    int b = blockIdx.x;
    int tid = threadIdx.x;
    __shared__ float ls[64][82];
    __shared__ float red[486][4];
    __shared__ float zz[10][81];
    __shared__ float tb[10][81];
    int q = tid / 81, p81 = tid - q*81;
    bool act = tid < 486;
    // zero row 81 of every chunk (pad rows 82..95 never read)
    for (int i = tid; i < 24*32; i += 512) {
        int ch = i >> 5, c = i & 31;
        xT2[(((size_t)b*24 + ch)*96 + 81)*32 + c] = __float2bfloat16(0.f);
    }
    if (tid < 2*32) {
        int ch = tid >> 5, c = tid & 31;
        yT2[(((size_t)b*2 + ch)*96 + 81)*32 + c] = __float2bfloat16(0.f);
    }
    float sx = 0.f;
    for (int c0 = 0; c0 < CCH; c0 += 64) {
        int ch0 = c0 >> 5;
        __syncthreads();
        for (int i = tid; i < 64*81; i += 512) {
            int c = i / 81, p = i - c*81;
            ls[c][p] = x[((size_t)b*CCH + c0 + c)*PP + p];
        }
        __syncthreads();
        for (int i = tid; i < 81*64; i += 512) {
            int p = i >> 6, c = i & 63;
            int ch = ch0 + (c >> 5), cc = c & 31;
            int s = cc >> 3, j = cc & 7;
            int slot = s ^ ((p >> 1) & 3);
            xT2[(((size_t)b*24 + ch)*96 + p)*32 + slot*8 + j] = __float2bfloat16(ls[c][p]);
        }
        if (act)
            for (int c = q; c < 64; c += 6)
                sx = fmaf(wh3[c0+c], ls[c][p81], sx);
    }
    __syncthreads();
    for (int i = tid; i < 64*81; i += 512) {
        int c = i / 81, p = i - c*81;
        ls[c][p] = y[((size_t)b*LCH + c)*PP + p];
    }
    __syncthreads();
    for (int i = tid; i < 81*64; i += 512) {
        int p = i >> 6, c = i & 63;
        int ch = c >> 5, cc = c & 31;
        int s = cc >> 3, j = cc & 7;
        int slot = s ^ ((p >> 1) & 3);
        yT2[(((size_t)b*2 + ch)*96 + p)*32 + slot*8 + j] = __float2bfloat16(ls[c][p]);
    }
    float sy = 0.f, s40 = 0.f, s41 = 0.f;
    if (act) {
        for (int c = q; c < 64; c += 6) {
            float v = ls[c][p81];
            sy  = fmaf(wl2[c], v, sy);
            s40 = fmaf(Wl3[c], v, s40);
            s41 = fmaf(Wl3[LCH+c], v, s41);
        }
        red[tid][0]=sx; red[tid][1]=sy; red[tid][2]=s40; red[tid][3]=s41;
    }
    __syncthreads();
    if (tid < 81) {
        float SX = 0.f, SY = 0.f, S40 = 0.f, S41 = 0.f;
        #pragma unroll
        for (int k = 0; k < 6; ++k) {
            SX  += red[tid+81*k][0];
            SY  += red[tid+81*k][1];
            S40 += red[tid+81*k][2];
            S41 += red[tid+81*k][3];
        }
        float t3a = SX + bh3[0];
        float t3b = SY + bl2[0];
        float f30 = W12[0]*t3a + W12[1]*t3b + b12[0];
        float f31 = W12[2]*t3a + W12[3]*t3b + b12[1];
        float f40 = S40 + bl3[0];
        float f41 = S41 + bl3[1];
        f3[(b*2+0)*PP+tid] = f30; f3[(b*2+1)*PP+tid] = f31;
        f4[(b*2+0)*PP+tid] = f40; f4[(b*2+1)*PP+tid] = f41;
        zz[0][tid]=f30; zz[1][tid]=f40; zz[2][tid]=f30*f30; zz[3][tid]=f40*f40; zz[4][tid]=f30*f40;
        zz[5][tid]=f31; zz[6][tid]=f41; zz[7][tid]=f31*f31; zz[8][tid]=f41*f41; zz[9][tid]=f31*f41;
    }
    __syncthreads();
    for (int i = tid; i < 10*81; i += 512) {
        int f = i / 81, p = i - f*81;
        int yy = p/9, xx = p - yy*9;
        float s = 0.f;
        #pragma unroll
        for (int d = -3; d <= 3; ++d) {
            int j = xx + d;
            j = (j < 0) ? (-1-j) : ((j > 8) ? (17-j) : j);
            s += zz[f][yy*9+j];
        }
        tb[f][p] = s * (1.f/7.f);
    }
    __syncthreads();
    for (int i = tid; i < 10*81; i += 512) {
        int f = i / 81, p = i - f*81;
        int yy = p/9, xx = p - yy*9;
        float s = 0.f;
        #pragma unroll
        for (int d = -3; d <= 3; ++d) {
            int j = yy + d;
            j = (j < 0) ? (-1-j) : ((j > 8) ? (17-j) : j);
            s += tb[f][j*9+xx];
        }
        Af[((size_t)b*10 + f)*81 + p] = s * (1.f/7.f);
    }
}

// ---------------- S3: box-7 along batch, 8 cols/block, grid 102 -------------
__global__ __launch_bounds__(256) void k_ssim_b2(
    const float* __restrict__ A, float* __restrict__ U)
{
    int col0 = blockIdx.x * 8;
    int tid = threadIdx.x;
    __shared__ float lsb[256][9];
    for (int i = tid; i < 256*8; i += 256) {
        int j = i >> 3, cc = i & 7;
        int col = col0 + cc;
        lsb[j][cc] = (col < 810) ? A[(size_t)j*810 + col] : 0.f;
    }
    __syncthreads();
    for (int i = tid; i < 256*8; i += 256) {
        int b = i >> 3, cc = i & 7;
        float s = 0.f;
        #pragma unroll
        for (int d = -3; d <= 3; ++d) {
            int j = b + d;
            j = (j < 0) ? (-1-j) : ((j > 255) ? (511-j) : j);
            s += lsb[j][cc];
        }
        int col = col0 + cc;
        if (col < 810) U[(size_t)b*810 + col] = s * (1.f/7.f);
    }
}

// ---------------- F: 256 thr; ssim_comb + pool + fc1(gelu) + fc2(leaky) -----
__global__ __launch_bounds__(256) void k_fc(
    const float* __restrict__ U, const float* __restrict__ f3,
    const float* __restrict__ f4, const float* __restrict__ wcc,
    const float* __restrict__ bcc,
    const float* __restrict__ wpool, const float* __restrict__ bpool,
    const float* __restrict__ T1, const float* __restrict__ bfc1,
    const float* __restrict__ T2, const float* __restrict__ bfc2,
    float* __restrict__ f22, float* __restrict__ ccs,
    float* __restrict__ xw)
{
    int b = blockIdx.x;
    int tid = threadIdx.x;
    __shared__ float xc[324];
    __shared__ float h1[324];
    __shared__ float pr[2][81], ps[2][81];
    const float cov = 343.f/342.f, C1c = 1e-4f, C2c = 9e-4f;
    for (int i = tid; i < 162; i += 256) {
        int k = i / 81, p = i - k*81;
        const float* u = U + (size_t)b*810 + (k*5)*81 + p;
        float ux = u[0], uy = u[81], uxx = u[162], uyy = u[243], uxy = u[324];
        float vx = cov*(uxx - ux*ux), vy = cov*(uyy - uy*uy), vxy = cov*(uxy - ux*uy);
        float S = ((2.f*ux*uy + C1c)*(2.f*vxy + C2c)) /
                  ((ux*ux + uy*uy + C1c)*(vx + vy + C2c));
        float a = f4[(b*2+k)*81+p] + S*f3[(b*2+k)*81+p];
        pr[k][p] = wcc[k]*a;
        ps[k][p] = wcc[k]*S;
    }
    __syncthreads();
    if (tid < 81) {
        float fv = pr[0][tid] + pr[1][tid] + bcc[0];
        float cv = ps[0][tid] + ps[1][tid] + bcc[0];
        f22[b*81+tid] = fv;
        ccs[b*81+tid] = cv;
        xc[tid] = fv; xc[243+tid] = fv;
    }
    __syncthreads();
    for (int i = tid; i < 162; i += 256) {
        int k = i / 81, p = i - k*81;
        int yy = p/9, xx = p - yy*9;
        float s = bpool[k];
        #pragma unroll
        for (int dy = -1; dy <= 1; ++dy)
            #pragma unroll
            for (int dx = -1; dx <= 1; ++dx) {
                int Y = yy+dy, X = xx+dx;
                if (Y >= 0 && Y < 9 && X >= 0 && X < 9)
                    s = fmaf(wpool[k*9 + (dy+1)*3 + (dx+1)], xc[Y*9+X], s);
            }
        xc[81+i] = s;
    }
    __syncthreads();
    for (int i = tid; i < 324; i += 256) {
        float s = bfc1[i];
        for (int j = 0; j < 324; ++j) s = fmaf(T1[(size_t)j*324 + i], xc[j], s);
        h1[i] = 0.5f*s*(1.f + erff(s*0.70710678118654752f));
    }
    __syncthreads();
    for (int qq = tid; qq < 81; qq += 256) {
        float s = bfc2[qq];
        for (int j = 0; j < 324; ++j) s = fmaf(T2[(size_t)j*81 + qq], h1[j], s);
        xw[b*81+qq] = (s > 0.f) ? s : 0.01f*s;
    }
}

// ---------------- K1 v11: fuse12 MFMA, 2 batches/block, direct-global -------
__global__ __launch_bounds__(512) void k_fuse12_mfma(
    const __hip_bfloat16* __restrict__ xT2,   // [B][24][96][32] swizzled image
    const __hip_bfloat16* __restrict__ yT2,   // [B][2][96][32]
    const __hip_bfloat16* __restrict__ Wh1p,
    const __hip_bfloat16* __restrict__ WAp,
    const __hip_bfloat16* __restrict__ WBp,
    const float* __restrict__ bh1, const float* __restrict__ beff,
    __hip_bfloat16* __restrict__ f1, __hip_bfloat16* __restrict__ f2)
{
    int oy = blockIdx.x;          // 0..7, o-extent 96; XCD = linear%8 = oy
    int b0 = blockIdx.y * 2;
    int tid = threadIdx.x;
    int w    = tid >> 6;          // 0..7
    int bi   = w >> 2;            // batch within pair
    int g    = (w >> 1) & 1;      // 0 -> f1 (Wh1), 1 -> f2 (WA, WB)
    int nh   = w & 1;             // n-half
    int lane = tid & 63;
    int l15  = lane & 15;
    int kg   = lane >> 4;

    int spoff[3];
    #pragma unroll
    for (int nl = 0; nl < 3; ++nl) {
        int p = (nh*3 + nl)*16 + l15;
        int sp = (p < PP) ? p : 81;
        spoff[nl] = sp*32 + ((kg ^ ((sp >> 1) & 3)) << 3);
    }

    f32x4 acc[6][3];
    #pragma unroll
    for (int m = 0; m < 6; ++m)
        #pragma unroll
        for (int nl = 0; nl < 3; ++nl)
            acc[m][nl] = (f32x4){0.f,0.f,0.f,0.f};

    int b = b0 + bi;
    const __hip_bfloat16* xb = xT2 + (size_t)b*24*CHW;
    const __hip_bfloat16* yb = yT2 + (size_t)b*2*CHW;
    const __hip_bfloat16* Wsel = g ? WAp : Wh1p;
    int otb = oy*6;

    for (int ch = 0; ch < 24; ++ch) {
        const __hip_bfloat16* cb = xb + (size_t)ch*CHW;
        short8v bf[3];
        #pragma unroll
        for (int nl = 0; nl < 3; ++nl)
            bf[nl] = *(const short8v*)&cb[spoff[nl]];
        short8v a[6];
        #pragma unroll
        for (int m = 0; m < 6; ++m)
            a[m] = *(const short8v*)(Wsel + ((((size_t)(otb + m))*24 + ch) << 9) + (lane<<3));
        #pragma unroll
        for (int nl = 0; nl < 3; ++nl)
            #pragma unroll
            for (int m = 0; m < 6; ++m)
                acc[m][nl] = __builtin_amdgcn_mfma_f32_16x16x32_bf16(a[m], bf[nl], acc[m][nl], 0, 0, 0);
    }

    if (g == 1) {
        for (int ch2 = 0; ch2 < 2; ++ch2) {
            const __hip_bfloat16* cb = yb + (size_t)ch2*CHW;
            short8v bf[3];
            #pragma unroll
            for (int nl = 0; nl < 3; ++nl)
                bf[nl] = *(const short8v*)&cb[spoff[nl]];
            short8v a[6];
            #pragma unroll
            for (int m = 0; m < 6; ++m)
                a[m] = *(const short8v*)(WBp + ((((size_t)(otb + m))*2 + ch2) << 9) + (lane<<3));
            #pragma unroll
            for (int nl = 0; nl < 3; ++nl)
                #pragma unroll
                for (int m = 0; m < 6; ++m)
                    acc[m][nl] = __builtin_amdgcn_mfma_f32_16x16x32_bf16(a[m], bf[nl], acc[m][nl], 0, 0, 0);
        }
    }

    __hip_bfloat16* dst = g ? f2 : f1;
    const float* bias = g ? beff : bh1;
    #pragma unroll
    for (int m = 0; m < 6; ++m) {
        #pragma unroll
        for (int r = 0; r < 4; ++r) {
            int o = (otb + m)*16 + kg*4 + r;
            float bb = bias[o];
            #pragma unroll
            for (int nl = 0; nl < 3; ++nl) {
                int p = (nh*3 + nl)*16 + l15;
                if (p < PP)
                    dst[((size_t)b*CCH + o)*PP + p] = __float2bfloat16(acc[m][nl][r] + bb);
            }
        }
    }
}

// ---------------- FZ: 512 thr; cor sums + alpha/gamma + image build ---------
__global__ __launch_bounds__(512) void k_finalize(
    const __hip_bfloat16* __restrict__ f1, const __hip_bfloat16* __restrict__ f2,
    const float* __restrict__ f22, const float* __restrict__ ccs,
    const float* __restrict__ xw,
    __hip_bfloat16* __restrict__ inb2)
{
    int b = blockIdx.x;
    int tid = threadIdx.x;
    __shared__ float red[486][5];
    __shared__ float sal[81], sga[81], scm[81];
    __shared__ float ls[64][82];
    // zero row 81 of every chunk
    for (int i = tid; i < 24*32; i += 512) {
        int ch = i >> 5, c = i & 31;
        inb2[(((size_t)b*24 + ch)*96 + 81)*32 + c] = __float2bfloat16(0.f);
    }
    bool act = tid < 486;
    float Sxx=0.f, Syy=0.f, Sxy=0.f, Sx=0.f, Sy=0.f;
    const __hip_bfloat16* A = f1 + (size_t)b*CCH*PP;
    const __hip_bfloat16* C = f2 + (size_t)b*CCH*PP;
    if (act) {
        for (int c0 = 0; c0 < CCH; c0 += 6) {
            float u = __bfloat162float(A[(size_t)c0*PP + tid]);
            float v = __bfloat162float(C[(size_t)c0*PP + tid]);
            Sxx = fmaf(u,u,Sxx); Syy = fmaf(v,v,Syy); Sxy = fmaf(u,v,Sxy);
            Sx += u; Sy += v;
        }
        red[tid][0]=Sxx; red[tid][1]=Syy; red[tid][2]=Sxy; red[tid][3]=Sx; red[tid][4]=Sy;
    }
    __syncthreads();
    if (tid < 81) {
        float xx=0.f, yy=0.f, xy=0.f, sx=0.f, sy=0.f;
        #pragma unroll
        for (int k = 0; k < 6; ++k) {
            xx += red[tid+81*k][0];
            yy += red[tid+81*k][1];
            xy += red[tid+81*k][2];
            sx += red[tid+81*k][3];
            sy += red[tid+81*k][4];
        }
        float cor1 = xy / fmaxf(sqrtf(xx)*sqrtf(yy), 1e-8f);
        float al = 0.5f*(1.f - cor1);
        float sum21 = sx + al*sy;
        float n21 = sqrtf(fmaxf(xx + 2.f*al*xy + al*al*yy, 0.f));
        int t = b*81 + tid;
        float fv = f22[t];
        float cor2 = (fv * sum21) / fmaxf(n21 * 27.712812921102035f * fabsf(fv), 1e-8f);
        float be = 0.5f*(1.f - cor2 + ccs[t]);
        sal[tid] = al;
        sga[tid] = be * fv;
        scm[tid] = 1.f + xw[t];
    }
    for (int c0 = 0; c0 < CCH; c0 += 64) {
        int ch0 = c0 >> 5;
        __syncthreads();
        for (int i = tid; i < 64*81; i += 512) {
            int c = i / 81, p = i - c*81;
            size_t gidx = ((size_t)b*CCH + c0 + c)*PP + p;
            float u = __bfloat162float(f1[gidx]);
            float v = __bfloat162float(f2[gidx]);
            ls[c][p] = scm[p]*(u + sal[p]*v + sga[p]);
        }
        __syncthreads();
        for (int i = tid; i < 81*64; i += 512) {
            int p = i >> 6, c = i & 63;
            int ch = ch0 + (c >> 5), cc = c & 31;
            int s = cc >> 3, j = cc & 7;
            int slot = s ^ ((p >> 1) & 3);
            inb2[(((size_t)b*24 + ch)*96 + p)*32 + slot*8 + j] = __float2bfloat16(ls[c][p]);
        }
    }
}

// ---------------- KB (R12-exact): bconv MFMA, 2 batches/block, 3-chunk groups
__global__ __launch_bounds__(256, 2) void k_bconv_mfma(
    const __hip_bfloat16* __restrict__ inb2,  // [B][24][96][32] swizzled image
    const __hip_bfloat16* __restrict__ Wp,    // packed [9][48][24][512]
    const float* __restrict__ bn_g, const float* __restrict__ bn_b,
    const float* __restrict__ bn_m, const float* __restrict__ bn_v,
    float* __restrict__ out)
{
    int oy = blockIdx.x;        // 0..7, o-extent 96; XCD = linear%8 = oy
    int b0 = blockIdx.y * 2;
    int tid = threadIdx.x;
    int w    = tid >> 6;        // 0..3
    int bi   = w >> 1;          // batch within pair
    int nh   = w & 1;           // n-half -> n-tiles {3*nh..3*nh+2}
    int lane = tid & 63;
    int l15  = lane & 15;
    int kg   = lane >> 4;

    __shared__ __align__(16) __hip_bfloat16 ls[6*CHW];   // [2 b][3 chunks][3072] = 36 KB

    int spoff[9][3];
    #pragma unroll
    for (int t = 0; t < 9; ++t) {
        int dy = t/3 - 1, dx = t%3 - 1;
        #pragma unroll
        for (int nl = 0; nl < 3; ++nl) {
            int p = (nh*3 + nl)*16 + l15;
            int yy = p/9, xx = p - yy*9;
            int Y = yy + dy, X = xx + dx;
            bool ok = (p < PP) && (Y >= 0) && (Y < 9) && (X >= 0) && (X < 9);
            int sp = ok ? (Y*9 + X) : 81;
            spoff[t][nl] = sp*32 + ((kg ^ ((sp >> 1) & 3)) << 3);
        }
    }

    f32x4 acc[6][3];
    #pragma unroll
    for (int m = 0; m < 6; ++m)
        #pragma unroll
        for (int nl = 0; nl < 3; ++nl)
            acc[m][nl] = (f32x4){0.f,0.f,0.f,0.f};

    const __hip_bfloat16* img0 = inb2 + (size_t)(b0    )*24*CHW;
    const __hip_bfloat16* img1 = inb2 + (size_t)(b0 + 1)*24*CHW;
    int otb = oy*6;

    for (int grp = 0; grp < 8; ++grp) {
        __syncthreads();
        // stage 3 chunks x 2 batches = 36 slabs of 1KB; 9 per wave
        #pragma unroll
        for (int k = 0; k < 9; ++k) {
            int it = w + 4*k;                 // 0..35
            int bb = it / 18;
            int r  = it - bb*18;
            int cc = r / 6, sub = r - cc*6;
            const __hip_bfloat16* src =
                (bb ? img1 : img0) + (size_t)(grp*3 + cc)*CHW + sub*512;
            GLL16(src + lane*8, &ls[(size_t)(bb*3 + cc)*CHW + sub*512]);
        }
        __syncthreads();
        for (int cc = 0; cc < 3; ++cc) {
            int ch = grp*3 + cc;
            const __hip_bfloat16* lb = &ls[(size_t)(bi*3 + cc)*CHW];
            #pragma unroll
            for (int t = 0; t < 9; ++t) {
                short8v a[6];
                #pragma unroll
                for (int m = 0; m < 6; ++m)
                    a[m] = *(const short8v*)(Wp + (((size_t)(t*48 + otb + m)*24 + ch) << 9) + (lane<<3));
                #pragma unroll
                for (int nl = 0; nl < 3; ++nl) {
                    short8v bf = *(const short8v*)&lb[spoff[t][nl]];
                    #pragma unroll
                    for (int m = 0; m < 6; ++m)
                        acc[m][nl] = __builtin_amdgcn_mfma_f32_16x16x32_bf16(a[m], bf, acc[m][nl], 0, 0, 0);
                }
            }
        }
    }

    int b = b0 + bi;
    #pragma unroll
    for (int m = 0; m < 6; ++m) {
        #pragma unroll
        for (int r = 0; r < 4; ++r) {
            int o = (otb + m)*16 + kg*4 + r;
            float sc = bn_g[o] * rsqrtf(bn_v[o] + 1e-5f);
            float mn = bn_m[o], bt = bn_b[o];
            #pragma unroll
            for (int nl = 0; nl < 3; ++nl) {
                int p = (nh*3 + nl)*16 + l15;
                if (p < PP) {
                    float v = (acc[m][nl][r] - mn) * sc + bt;
                    out[((size_t)b*CCH + o)*PP + p] = (v > 0.f) ? v : 0.01f*v;
                }
            }
        }
    }
}

extern "C" void kernel_launch(void* const* d_in, const int* in_sizes, int n_in,
                              void* d_out, int out_size, void* d_ws, size_t ws_size,
                              hipStream_t stream)
{
    (void)in_sizes; (void)n_in; (void)out_size; (void)ws_size;
    const float* x    = (const float*)d_in[0];
    const float* y    = (const float*)d_in[1];
    const float* Wh1  = (const float*)d_in[2];
    const float* bh1  = (const float*)d_in[3];
    const float* W11  = (const float*)d_in[4];
    const float* b11  = (const float*)d_in[5];
    const float* Wh2  = (const float*)d_in[6];
    const float* bh2  = (const float*)d_in[7];
    const float* Wl1  = (const float*)d_in[8];
    const float* bl1  = (const float*)d_in[9];
    const float* wh3  = (const float*)d_in[10];
    const float* bh3  = (const float*)d_in[11];
    const float* wl2  = (const float*)d_in[12];
    const float* bl2  = (const float*)d_in[13];
    const float* W12  = (const float*)d_in[14];
    const float* b12  = (const float*)d_in[15];
    const float* Wl3  = (const float*)d_in[16];
    const float* bl3  = (const float*)d_in[17];
    const float* wcc  = (const float*)d_in[18];
    const float* bcc  = (const float*)d_in[19];
    const float* wpool= (const float*)d_in[20];
    const float* bpool= (const float*)d_in[21];
    const float* Wfc1 = (const float*)d_in[22];
    const float* bfc1 = (const float*)d_in[23];
    const float* Wfc2 = (const float*)d_in[24];
    const float* bfc2 = (const float*)d_in[25];
    const float* Wb   = (const float*)d_in[26];
    const float* bng  = (const float*)d_in[27];
    const float* bnb  = (const float*)d_in[28];
    const float* bnm  = (const float*)d_in[29];
    const float* bnv  = (const float*)d_in[30];
    float* out = (float*)d_out;
    float* ws = (float*)d_ws;

    size_t off = 0;
    float* beff  = ws + off; off += CCH;
    float* f3    = ws + off; off += BATCH*2*PP;
    float* f4    = ws + off; off += BATCH*2*PP;
    float* Af    = ws + off; off += BATCH*10*PP;
    float* Uf    = ws + off; off += BATCH*10*PP;
    float* f22   = ws + off; off += BATCH*PP;
    float* ccs   = ws + off; off += BATCH*PP;
    float* xw    = ws + off; off += BATCH*PP;
    float* T1    = ws + off; off += 324*324;
    float* T2    = ws + off; off += 324*81;
    off = (off + 3) & ~(size_t)3;   // 16B-align bf16 region
    __hip_bfloat16* Wh1p = (__hip_bfloat16*)(ws + off); off += (size_t)48*24*512/2;
    __hip_bfloat16* WAp  = (__hip_bfloat16*)(ws + off); off += (size_t)48*24*512/2;
    __hip_bfloat16* WBp  = (__hip_bfloat16*)(ws + off); off += (size_t)48*2*512/2;
    __hip_bfloat16* yT2  = (__hip_bfloat16*)(ws + off); off += (size_t)BATCH*2*CHW/2;
    __hip_bfloat16* f1b  = (__hip_bfloat16*)(ws + off); off += (size_t)BATCH*CCH*PP/2;
    __hip_bfloat16* f2b  = (__hip_bfloat16*)(ws + off); off += (size_t)BATCH*CCH*PP/2;
    off = (off + 3) & ~(size_t)3;
    __hip_bfloat16* inb2 = (__hip_bfloat16*)(ws + off); off += (size_t)BATCH*24*CHW/2;
    __hip_bfloat16* Wp   = (__hip_bfloat16*)(ws + off); off += (size_t)9*48*24*512/2;
    // xT2 aliases inb2: fuse12 consumes xT2 before k_finalize overwrites it
    __hip_bfloat16* xT2 = inb2;

    k_prep<<<dim3(CCH + 288 + 411), dim3(256), 0, stream>>>(
        W11, Wh2, Wl1, bh2, bl1, b11, Wh1, Wb, Wfc1, Wfc2,
        WAp, WBp, Wh1p, beff, Wp, T1, T2);
    k_xprep_f34<<<dim3(BATCH), dim3(512), 0, stream>>>(x, y, wh3, bh3, wl2, bl2, W12, b12, Wl3, bl3, xT2, yT2, f3, f4, Af);
    k_ssim_b2<<<dim3(102), dim3(256), 0, stream>>>(Af, Uf);
    k_fc<<<dim3(BATCH), dim3(256), 0, stream>>>(Uf, f3, f4, wcc, bcc, wpool, bpool, T1, bfc1, T2, bfc2, f22, ccs, xw);
    k_fuse12_mfma<<<dim3(8, BATCH/2), dim3(512), 0, stream>>>(xT2, yT2, Wh1p, WAp, WBp, bh1, beff, f1b, f2b);
    k_finalize<<<dim3(BATCH), dim3(512), 0, stream>>>(f1b, f2b, f22, ccs, xw, inb2);
    k_bconv_mfma<<<dim3(8, BATCH/2), dim3(256), 0, stream>>>(inb2, Wp, bng, bnb, bnm, bnv, out);
}